// Round 2
// baseline (33058.887 us; speedup 1.0000x reference)
//
#include <hip/hip_runtime.h>
#include <cstdint>
#include <math.h>

#define NB 16
#define DM 512
#define NH 8
#define DFF_ 2048

// ---------------- threefry2x32 (JAX-compatible) ----------------
__host__ __device__ inline void tf2x32(uint32_t k0, uint32_t k1,
                                       uint32_t x0, uint32_t x1,
                                       uint32_t* o0, uint32_t* o1) {
  uint32_t ks0 = k0, ks1 = k1, ks2 = k0 ^ k1 ^ 0x1BD11BDAu;
  x0 += ks0; x1 += ks1;
#define TF_RND(r) { x0 += x1; x1 = (x1 << (r)) | (x1 >> (32 - (r))); x1 ^= x0; }
  TF_RND(13) TF_RND(15) TF_RND(26) TF_RND(6)
  x0 += ks1; x1 += ks2 + 1u;
  TF_RND(17) TF_RND(29) TF_RND(16) TF_RND(24)
  x0 += ks2; x1 += ks0 + 2u;
  TF_RND(13) TF_RND(15) TF_RND(26) TF_RND(6)
  x0 += ks0; x1 += ks1 + 3u;
  TF_RND(17) TF_RND(29) TF_RND(16) TF_RND(24)
  x0 += ks1; x1 += ks2 + 4u;
  TF_RND(13) TF_RND(15) TF_RND(26) TF_RND(6)
  x0 += ks2; x1 += ks0 + 5u;
#undef TF_RND
  *o0 = x0; *o1 = x1;
}

// idx[j] = lower_bits[j] & (L-1), lower_bits = threefry_2x32(k2, iota(n))
__global__ void gen_idx_kernel(int* __restrict__ idx, uint32_t k0, uint32_t k1,
                               int n, int mask) {
  int j = blockIdx.x * 256 + threadIdx.x;
  if (j >= n) return;
  int half = n >> 1;
  uint32_t o0, o1;
  if (j < half) {
    tf2x32(k0, k1, (uint32_t)j, (uint32_t)(j + half), &o0, &o1);
    idx[j] = (int)(o0 & (uint32_t)mask);
  } else {
    tf2x32(k0, k1, (uint32_t)(j - half), (uint32_t)j, &o0, &o1);
    idx[j] = (int)(o1 & (uint32_t)mask);
  }
}

// ---------------- block reduce helper (256 threads, wave64) ----------------
__device__ inline float blk_reduce_sum(float v) {
  __shared__ float s[4];
  for (int o = 32; o > 0; o >>= 1) v += __shfl_down(v, o);
  int lane = threadIdx.x & 63, w = threadIdx.x >> 6;
  if (lane == 0) s[w] = v;
  __syncthreads();
  float r = s[0] + s[1] + s[2] + s[3];
  __syncthreads();
  return r;
}

// ---------------- embedding: h = x @ emb_W + emb_b ----------------
__global__ void embed_kernel(const float* __restrict__ x, const float* __restrict__ W,
                             const float* __restrict__ bias, float* __restrict__ h) {
  size_t gid = (size_t)blockIdx.x * 256 + threadIdx.x;
  int o = (int)(gid & 511);
  size_t bl = gid >> 9;
  const float* xr = x + bl * 7;
  float acc = bias[o];
#pragma unroll
  for (int i = 0; i < 7; ++i) acc += xr[i] * W[i * 512 + o];
  h[gid] = acc;
}

// ---------------- generic tiled f32 GEMM ----------------
// C(M,N) = A(M,K) @ B + bias ; BMODE 0: B is (K,N) row-major ; 1: B is (N,K) row-major (B^T)
// ACT 0: none, 1: exact GELU.  ACC 1: C += result (residual accumulate)
__device__ inline float gelu_exact(float c) {
  return 0.5f * c * (1.0f + erff(c * 0.70710678118654752f));
}

template <int BMODE, int ACT, int ACC>
__global__ __launch_bounds__(256) void gemm_f32(
    const float* __restrict__ A, const float* __restrict__ Bm,
    const float* __restrict__ bias, float* __restrict__ C,
    int M, int N, int K) {
  __shared__ float As[16][65];
  __shared__ float Bs[16][65];
  int bm = blockIdx.y, bn = blockIdx.x;
  int tid = threadIdx.x;
  int tr = tid >> 4, tc = tid & 15;
  float acc[4][4] = {};
  int arow = tid >> 2;
  int acol = (tid & 3) * 4;
  const float* Ab = A + (size_t)(bm * 64 + arow) * K;

  for (int k0 = 0; k0 < K; k0 += 16) {
    float4 av = *(const float4*)(Ab + k0 + acol);
    As[acol + 0][arow] = av.x;
    As[acol + 1][arow] = av.y;
    As[acol + 2][arow] = av.z;
    As[acol + 3][arow] = av.w;
    if (BMODE == 0) {
      int brow = tid >> 4;
      int bcol = (tid & 15) * 4;
      float4 bv = *(const float4*)(Bm + (size_t)(k0 + brow) * N + bn * 64 + bcol);
      Bs[brow][bcol + 0] = bv.x;
      Bs[brow][bcol + 1] = bv.y;
      Bs[brow][bcol + 2] = bv.z;
      Bs[brow][bcol + 3] = bv.w;
    } else {
      int bnn = tid >> 2;
      int bkk = (tid & 3) * 4;
      float4 bv = *(const float4*)(Bm + (size_t)(bn * 64 + bnn) * K + k0 + bkk);
      Bs[bkk + 0][bnn] = bv.x;
      Bs[bkk + 1][bnn] = bv.y;
      Bs[bkk + 2][bnn] = bv.z;
      Bs[bkk + 3][bnn] = bv.w;
    }
    __syncthreads();
#pragma unroll
    for (int kk = 0; kk < 16; ++kk) {
      float a[4], b[4];
#pragma unroll
      for (int i = 0; i < 4; ++i) a[i] = As[kk][tr * 4 + i];
#pragma unroll
      for (int j = 0; j < 4; ++j) b[j] = Bs[kk][tc * 4 + j];
#pragma unroll
      for (int i = 0; i < 4; ++i)
#pragma unroll
        for (int j = 0; j < 4; ++j) acc[i][j] += a[i] * b[j];
    }
    __syncthreads();
  }
#pragma unroll
  for (int i = 0; i < 4; ++i) {
    int row = bm * 64 + tr * 4 + i;
#pragma unroll
    for (int j = 0; j < 4; ++j) {
      int col = bn * 64 + tc * 4 + j;
      float c = acc[i][j] + bias[col];
      if (ACT == 1) c = gelu_exact(c);
      size_t oi = (size_t)row * N + col;
      if (ACC == 1) c += C[oi];
      C[oi] = c;
    }
  }
}

// ---------------- LN (in-place, row = 512) ----------------
__global__ __launch_bounds__(256) void ln_inplace(float* __restrict__ h,
                                                  const float* __restrict__ g,
                                                  const float* __restrict__ b) {
  size_t row = blockIdx.x;
  float* hr = h + row * 512;
  int t = threadIdx.x;
  float x0 = hr[t], x1 = hr[t + 256];
  float mean = blk_reduce_sum(x0 + x1) * (1.0f / 512.0f);
  float d0 = x0 - mean, d1 = x1 - mean;
  float var = blk_reduce_sum(d0 * d0 + d1 * d1) * (1.0f / 512.0f);
  float rstd = rsqrtf(var + 1e-5f);
  hr[t] = d0 * rstd * g[t] + b[t];
  hr[t + 256] = d1 * rstd * g[t + 256] + b[t + 256];
}

// ---------------- prob-sparse M scores (chunk-local batch) ----------------
__global__ __launch_bounds__(256) void prob_scores(const float* __restrict__ q,
                                                   const float* __restrict__ k,
                                                   const int* __restrict__ idx,
                                                   float* __restrict__ Mout,
                                                   int L, int S) {
  int gid = blockIdx.x * 256 + threadIdx.x;  // over CB*H*L
  int l = gid % L;
  int bh = gid / L;
  int hh = bh & 7;
  int b = bh >> 3;
  const float* qr = q + ((size_t)(b * L + l)) * 512 + hh * 64;
  float4 qv[16];
#pragma unroll
  for (int u = 0; u < 16; ++u) qv[u] = ((const float4*)qr)[u];
  float m = -INFINITY, ssum = 0.0f;
  for (int s = 0; s < S; ++s) {
    int j = idx[l * S + s];
    const float* kr = k + ((size_t)(b * L + j)) * 512 + hh * 64;
    float dot = 0.0f;
#pragma unroll
    for (int u = 0; u < 16; ++u) {
      float4 kv = ((const float4*)kr)[u];
      dot += qv[u].x * kv.x + qv[u].y * kv.y + qv[u].z * kv.z + qv[u].w * kv.w;
    }
    m = fmaxf(m, dot);
    ssum += dot;
  }
  Mout[(size_t)bh * L + l] = m - ssum / (float)L;
}

// ---------------- top-k (iterative argmax, lower index wins ties) ----------------
__global__ __launch_bounds__(256) void topk_kernel(const float* __restrict__ Mbuf,
                                                   int* __restrict__ top_idx,
                                                   int L, int S) {
  int bh = blockIdx.x;
  __shared__ float vals[4096];
  __shared__ float rv[256];
  __shared__ int ri[256];
  const float* Mr = Mbuf + (size_t)bh * L;
  int t = threadIdx.x;
  for (int j = t; j < L; j += 256) vals[j] = Mr[j];
  __syncthreads();
  for (int it = 0; it < S; ++it) {
    float bv = -INFINITY;
    int bi = L;
    for (int j = t; j < L; j += 256) {
      float v = vals[j];
      if (v > bv || (v == bv && j < bi)) { bv = v; bi = j; }
    }
    rv[t] = bv; ri[t] = bi;
    __syncthreads();
    for (int s2 = 128; s2 > 0; s2 >>= 1) {
      if (t < s2) {
        float ov = rv[t + s2]; int oi = ri[t + s2];
        if (ov > rv[t] || (ov == rv[t] && oi < ri[t])) { rv[t] = ov; ri[t] = oi; }
      }
      __syncthreads();
    }
    if (t == 0) {
      top_idx[bh * S + it] = ri[0];
      vals[ri[0]] = -INFINITY;
    }
    __syncthreads();
  }
}

// ---------------- mean of V over sequence ----------------
__global__ __launch_bounds__(256) void mean_v_kernel(const float* __restrict__ v,
                                                     float* __restrict__ mv, int L) {
  int bh = blockIdx.x;
  int b = bh >> 3, hh = bh & 7;
  int t = threadIdx.x;
  int d = t & 63, p = t >> 6;
  float acc = 0.0f;
  for (int j = p; j < L; j += 4) acc += v[((size_t)(b * L + j)) * 512 + hh * 64 + d];
  __shared__ float part[4][64];
  part[p][d] = acc;
  __syncthreads();
  if (p == 0)
    mv[bh * 64 + d] = (part[0][d] + part[1][d] + part[2][d] + part[3][d]) / (float)L;
}

// ---------------- fill ctx with broadcast mean ----------------
__global__ void fill_ctx(float* __restrict__ ctx, const float* __restrict__ mv, int L) {
  size_t gid = (size_t)blockIdx.x * 256 + threadIdx.x;  // CB*L*512
  int c = (int)(gid & 511);
  size_t bl = gid >> 9;
  int b = (int)(bl / (size_t)L);
  ctx[gid] = mv[(b * 8 + (c >> 6)) * 64 + (c & 63)];
}

// ---------------- full attention for selected queries, scatter into ctx ----------------
__global__ __launch_bounds__(256) void attn_update(const float* __restrict__ q,
                                                   const float* __restrict__ k,
                                                   const float* __restrict__ v,
                                                   const int* __restrict__ top_idx,
                                                   float* __restrict__ ctx,
                                                   int L, int S) {
  __shared__ float qs[64];
  __shared__ float sc[4096];
  __shared__ float red[256];
  __shared__ float part[4][64];
  int blk = blockIdx.x;
  int u = blk % S;
  int bh = blk / S;
  int hh = bh & 7, b = bh >> 3;
  int t = threadIdx.x;
  int l = top_idx[bh * S + u];
  if (t < 64) qs[t] = q[((size_t)(b * L + l)) * 512 + hh * 64 + t];
  __syncthreads();
  float lmax = -INFINITY;
  for (int j = t; j < L; j += 256) {
    const float* kr = k + ((size_t)(b * L + j)) * 512 + hh * 64;
    float dot = 0.0f;
#pragma unroll
    for (int d4 = 0; d4 < 16; ++d4) {
      float4 kv = ((const float4*)kr)[d4];
      dot += qs[d4 * 4 + 0] * kv.x + qs[d4 * 4 + 1] * kv.y +
             qs[d4 * 4 + 2] * kv.z + qs[d4 * 4 + 3] * kv.w;
    }
    dot *= 0.125f;  // 1/sqrt(64)
    sc[j] = dot;
    lmax = fmaxf(lmax, dot);
  }
  red[t] = lmax;
  __syncthreads();
  for (int s2 = 128; s2 > 0; s2 >>= 1) {
    if (t < s2) red[t] = fmaxf(red[t], red[t + s2]);
    __syncthreads();
  }
  float m = red[0];
  __syncthreads();
  float lsum = 0.0f;
  for (int j = t; j < L; j += 256) {
    float e = expf(sc[j] - m);
    sc[j] = e;
    lsum += e;
  }
  red[t] = lsum;
  __syncthreads();
  for (int s2 = 128; s2 > 0; s2 >>= 1) {
    if (t < s2) red[t] += red[t + s2];
    __syncthreads();
  }
  float Z = red[0];
  __syncthreads();
  int d = t & 63, p = t >> 6;
  float acc = 0.0f;
  for (int j = p; j < L; j += 4)
    acc += sc[j] * v[((size_t)(b * L + j)) * 512 + hh * 64 + d];
  part[p][d] = acc;
  __syncthreads();
  if (p == 0)
    ctx[((size_t)(b * L + l)) * 512 + hh * 64 + d] =
        (part[0][d] + part[1][d] + part[2][d] + part[3][d]) / Z;
}

// ---------------- conv (circular, k=3) as GEMM K=1536 + BN + ELU ----------------
__global__ __launch_bounds__(256) void conv_gemm(const float* __restrict__ hsrc,
                                                 const float* __restrict__ W,
                                                 const float* __restrict__ cbias,
                                                 const float* __restrict__ bng,
                                                 const float* __restrict__ bnb,
                                                 float* __restrict__ C, int L) {
  __shared__ float As[16][65];
  __shared__ float Bs[16][65];
  int bm = blockIdx.y, bn = blockIdx.x;
  int tid = threadIdx.x;
  int tr = tid >> 4, tc = tid & 15;
  float acc[4][4] = {};
  int arow = tid >> 2;
  int acol = (tid & 3) * 4;
  int m = bm * 64 + arow;
  int b = m / L, tpos = m % L;
  const int K = 1536;
  for (int k0 = 0; k0 < K; k0 += 16) {
    int kk0 = k0 + acol;
    int dt = kk0 >> 9;
    int ii = kk0 & 511;
    int trow = tpos + dt - 1;
    if (trow < 0) trow += L;
    if (trow >= L) trow -= L;
    float4 av = *(const float4*)(hsrc + ((size_t)(b * L + trow)) * 512 + ii);
    As[acol + 0][arow] = av.x;
    As[acol + 1][arow] = av.y;
    As[acol + 2][arow] = av.z;
    As[acol + 3][arow] = av.w;
    int bnn = tid >> 2;
    int bkk = (tid & 3) * 4;
#pragma unroll
    for (int uu = 0; uu < 4; ++uu) {
      int kq = k0 + bkk + uu;
      int dtb = kq >> 9, ib = kq & 511;
      Bs[bkk + uu][bnn] = W[((size_t)(bn * 64 + bnn) * 512 + ib) * 3 + dtb];
    }
    __syncthreads();
#pragma unroll
    for (int kk = 0; kk < 16; ++kk) {
      float a[4], bb[4];
#pragma unroll
      for (int i = 0; i < 4; ++i) a[i] = As[kk][tr * 4 + i];
#pragma unroll
      for (int j = 0; j < 4; ++j) bb[j] = Bs[kk][tc * 4 + j];
#pragma unroll
      for (int i = 0; i < 4; ++i)
#pragma unroll
        for (int j = 0; j < 4; ++j) acc[i][j] += a[i] * bb[j];
    }
    __syncthreads();
  }
  const float bnscale = 0.9999950000374996f;  // 1/sqrt(1 + 1e-5)
#pragma unroll
  for (int i = 0; i < 4; ++i) {
    int row = bm * 64 + tr * 4 + i;
#pragma unroll
    for (int j = 0; j < 4; ++j) {
      int col = bn * 64 + tc * 4 + j;
      float c = acc[i][j] + cbias[col];
      c = c * bnscale * bng[col] + bnb[col];
      c = c > 0.0f ? c : expm1f(c);
      C[(size_t)row * 512 + col] = c;
    }
  }
}

// ---------------- maxpool window 3 stride 2 (with -inf edge pad) ----------------
__global__ void maxpool_kernel(const float* __restrict__ y, float* __restrict__ hout,
                               int L) {
  size_t gid = (size_t)blockIdx.x * 256 + threadIdx.x;  // CB*(L/2)*512
  int Lh = L >> 1;
  int o = (int)(gid & 511);
  size_t bj = gid >> 9;
  int j = (int)(bj % (size_t)Lh);
  int b = (int)(bj / (size_t)Lh);
  const float* base = y + ((size_t)(b * L + 2 * j)) * 512 + o;
  float mx = base[0];
  if (j > 0) mx = fmaxf(mx, base[-512]);
  mx = fmaxf(mx, base[512]);
  hout[gid] = mx;
}

// ---------------- final LN + projection (only first 47 rows) ----------------
__global__ __launch_bounds__(256) void final_ln_proj(const float* __restrict__ h,
                                                     const float* __restrict__ g,
                                                     const float* __restrict__ bb,
                                                     const float* __restrict__ pw,
                                                     const float* __restrict__ pb,
                                                     float* __restrict__ out, int L) {
  int b = blockIdx.x / 47, l = blockIdx.x % 47;
  const float* hr = h + ((size_t)(b * L + l)) * 512;
  int t = threadIdx.x;
  float x0 = hr[t], x1 = hr[t + 256];
  float mean = blk_reduce_sum(x0 + x1) * (1.0f / 512.0f);
  float d0 = x0 - mean, d1 = x1 - mean;
  float var = blk_reduce_sum(d0 * d0 + d1 * d1) * (1.0f / 512.0f);
  float rstd = rsqrtf(var + 1e-5f);
  float y0 = d0 * rstd * g[t] + bb[t];
  float y1 = d1 * rstd * g[t + 256] + bb[t + 256];
  float dot = blk_reduce_sum(y0 * pw[t] + y1 * pw[t + 256]);
  if (t == 0) out[b * 47 + l] = dot + pb[0];
}

// ---------------- launcher ----------------
extern "C" void kernel_launch(void* const* d_in, const int* in_sizes, int n_in,
                              void* d_out, int out_size, void* d_ws, size_t ws_size,
                              hipStream_t stream) {
  const float* x = (const float*)d_in[0];
  const float* emb_W = (const float*)d_in[1];
  const float* emb_b = (const float*)d_in[2];
  const float* Wq = (const float*)d_in[3];
  const float* bq = (const float*)d_in[4];
  const float* Wk = (const float*)d_in[5];
  const float* bk = (const float*)d_in[6];
  const float* Wv = (const float*)d_in[7];
  const float* bv = (const float*)d_in[8];
  const float* Wo = (const float*)d_in[9];
  const float* bo = (const float*)d_in[10];
  const float* fW1 = (const float*)d_in[11];
  const float* fb1 = (const float*)d_in[12];
  const float* fW2 = (const float*)d_in[13];
  const float* fb2 = (const float*)d_in[14];
  const float* ln1g = (const float*)d_in[15];
  const float* ln1b = (const float*)d_in[16];
  const float* ln2g = (const float*)d_in[17];
  const float* ln2b = (const float*)d_in[18];
  const float* cW = (const float*)d_in[19];
  const float* cb = (const float*)d_in[20];
  const float* bng = (const float*)d_in[21];
  const float* bnb = (const float*)d_in[22];
  const float* flng = (const float*)d_in[23];
  const float* flnb = (const float*)d_in[24];
  const float* pW = (const float*)d_in[25];
  const float* pb = (const float*)d_in[26];
  float* out = (float*)d_out;

  // choose batch-group size CB from ws_size (deterministic per session)
  int CB = 4;
  while (CB > 1) {
    size_t need = 33554432ull + 4ull * CB * 4096 * 512 + (size_t)CB * 8 * 4096 +
                  (size_t)CB * 8 * 64 + (size_t)CB * 8 * 48 + 196608ull + 1024ull;
    if (need * 4 <= ws_size) break;
    CB >>= 1;
  }

  float* ws = (float*)d_ws;
  size_t off = 0;
  float* h = ws;                       off += 33554432ull;               // B*4096*512
  size_t seg0 = (size_t)CB * 4096 * 512;
  float* bufQ = ws + off;              off += seg0;
  float* bufK = ws + off;              off += seg0;
  float* bufV = ws + off;              off += seg0;
  float* bufX = ws + off;              off += seg0;   // ctx
  float* Mbuf = ws + off;              off += (size_t)CB * 8 * 4096;
  float* mv   = ws + off;              off += (size_t)CB * 8 * 64;
  int* topidx = (int*)(ws + off);      off += (size_t)CB * 8 * 48;
  int* idxbuf = (int*)(ws + off);      off += 196608ull;

  // embedding: full h
  {
    size_t total = (size_t)NB * 4096 * DM;
    embed_kernel<<<(int)(total / 256), 256, 0, stream>>>(x, emb_W, emb_b, h);
  }

  int L = 4096;
  for (int i = 0; i < 3; ++i) {
    int S = (i == 0) ? 45 : (i == 1) ? 40 : 35;
    int ngroups = NB / CB;
    int Mg = CB * L;                     // rows per group
    size_t segL = (size_t)Mg * 512;

    // --- derive JAX randint lower-bits key on host ---
    uint32_t fa, fbk;
    tf2x32(0u, 42u, 0u, (uint32_t)i, &fa, &fbk);   // fold_in(key(42), i)
    uint32_t a0, b0, a1, b1;
    tf2x32(fa, fbk, 0u, 2u, &a0, &b0);             // split -> keys
    tf2x32(fa, fbk, 1u, 3u, &a1, &b1);
    uint32_t k2hi = b0, k2lo = b1;                 // second split key

    int n = L * S;
    gen_idx_kernel<<<(n + 255) / 256, 256, 0, stream>>>(idxbuf, k2hi, k2lo, n, L - 1);

    // ---- attention, per batch group ----
    for (int g = 0; g < ngroups; ++g) {
      float* hg = h + (size_t)g * segL;
      dim3 gqkv(DM / 64, Mg / 64);
      gemm_f32<0, 0, 0><<<gqkv, 256, 0, stream>>>(hg, Wq + (size_t)i * DM * DM, bq + i * DM, bufQ, Mg, DM, DM);
      gemm_f32<0, 0, 0><<<gqkv, 256, 0, stream>>>(hg, Wk + (size_t)i * DM * DM, bk + i * DM, bufK, Mg, DM, DM);
      gemm_f32<0, 0, 0><<<gqkv, 256, 0, stream>>>(hg, Wv + (size_t)i * DM * DM, bv + i * DM, bufV, Mg, DM, DM);

      prob_scores<<<(CB * NH * L) / 256, 256, 0, stream>>>(bufQ, bufK, idxbuf, Mbuf, L, S);
      topk_kernel<<<CB * NH, 256, 0, stream>>>(Mbuf, topidx, L, S);
      mean_v_kernel<<<CB * NH, 256, 0, stream>>>(bufV, mv, L);
      fill_ctx<<<(int)(segL / 256), 256, 0, stream>>>(bufX, mv, L);
      attn_update<<<CB * NH * S, 256, 0, stream>>>(bufQ, bufK, bufV, topidx, bufX, L, S);

      // attn out proj, accumulate into h (residual)
      gemm_f32<0, 0, 1><<<gqkv, 256, 0, stream>>>(bufX, Wo + (size_t)i * DM * DM, bo + i * DM, hg, Mg, DM, DM);
    }
    ln_inplace<<<NB * L, 256, 0, stream>>>(h, ln1g + i * DM, ln1b + i * DM);

    // ---- FF, row-chunked through the 4-seg region ----
    int rows = NB * L;
    int R = CB * 4096;   // rows per chunk; 4*seg0/2048 columns capacity
    for (int r0 = 0; r0 < rows; r0 += R) {
      float* hr = h + (size_t)r0 * 512;
      dim3 g1(DFF_ / 64, R / 64);
      gemm_f32<1, 1, 0><<<g1, 256, 0, stream>>>(hr, fW1 + (size_t)i * DFF_ * DM, fb1 + i * DFF_, bufQ, R, DFF_, DM);
      dim3 g2(DM / 64, R / 64);
      gemm_f32<1, 0, 1><<<g2, 256, 0, stream>>>(bufQ, fW2 + (size_t)i * DM * DFF_, fb2 + i * DM, hr, R, DM, DFF_);
    }
    ln_inplace<<<NB * L, 256, 0, stream>>>(h, ln2g + i * DM, ln2b + i * DM);

    // ---- conv + maxpool, per batch group (in-place left-compaction) ----
    if (i < 2) {
      int Lh = L / 2;
      for (int g = 0; g < ngroups; ++g) {
        float* hg = h + (size_t)g * segL;
        dim3 gc(DM / 64, Mg / 64);
        conv_gemm<<<gc, 256, 0, stream>>>(hg, cW + (size_t)i * DM * DM * 3, cb + i * DM,
                                          bng + i * DM, bnb + i * DM, bufQ, L);
        size_t tot = (size_t)CB * Lh * 512;
        maxpool_kernel<<<(int)(tot / 256), 256, 0, stream>>>(
            bufQ, h + (size_t)g * CB * Lh * 512, L);
      }
      L = Lh;
    }
  }

  final_ln_proj<<<NB * 47, 256, 0, stream>>>(h, flng, flnb, pW, pb, out, L);
}

// Round 3
// 10222.813 us; speedup vs baseline: 3.2338x; 3.2338x over previous
//
#include <hip/hip_runtime.h>
#include <cstdint>
#include <math.h>

#define NB 16
#define DM 512
#define NH 8
#define DFF_ 2048

typedef unsigned short ushort_t;
typedef __bf16 bf16x8 __attribute__((ext_vector_type(8)));
typedef float f32x4 __attribute__((ext_vector_type(4)));

// ---------------- bf16 helpers ----------------
__device__ __forceinline__ ushort_t f2b(float f) {  // RNE f32 -> bf16 bits
  uint32_t u = __float_as_uint(f);
  uint32_t r = (u + 0x7FFFu + ((u >> 16) & 1u)) >> 16;
  return (ushort_t)r;
}
__device__ __forceinline__ float bu2f(ushort_t x) {
  return __uint_as_float((uint32_t)x << 16);
}
__device__ __forceinline__ float b2f_lo(uint32_t u) { return __uint_as_float(u << 16); }
__device__ __forceinline__ float b2f_hi(uint32_t u) { return __uint_as_float(u & 0xFFFF0000u); }

// ---------------- threefry2x32 (JAX-compatible) ----------------
__host__ __device__ inline void tf2x32(uint32_t k0, uint32_t k1,
                                       uint32_t x0, uint32_t x1,
                                       uint32_t* o0, uint32_t* o1) {
  uint32_t ks0 = k0, ks1 = k1, ks2 = k0 ^ k1 ^ 0x1BD11BDAu;
  x0 += ks0; x1 += ks1;
#define TF_RND(r) { x0 += x1; x1 = (x1 << (r)) | (x1 >> (32 - (r))); x1 ^= x0; }
  TF_RND(13) TF_RND(15) TF_RND(26) TF_RND(6)
  x0 += ks1; x1 += ks2 + 1u;
  TF_RND(17) TF_RND(29) TF_RND(16) TF_RND(24)
  x0 += ks2; x1 += ks0 + 2u;
  TF_RND(13) TF_RND(15) TF_RND(26) TF_RND(6)
  x0 += ks0; x1 += ks1 + 3u;
  TF_RND(17) TF_RND(29) TF_RND(16) TF_RND(24)
  x0 += ks1; x1 += ks2 + 4u;
  TF_RND(13) TF_RND(15) TF_RND(26) TF_RND(6)
  x0 += ks2; x1 += ks0 + 5u;
#undef TF_RND
  *o0 = x0; *o1 = x1;
}

__global__ void gen_idx_kernel(int* __restrict__ idx, uint32_t k0, uint32_t k1,
                               int n, int mask) {
  int j = blockIdx.x * 256 + threadIdx.x;
  if (j >= n) return;
  int half = n >> 1;
  uint32_t o0, o1;
  if (j < half) {
    tf2x32(k0, k1, (uint32_t)j, (uint32_t)(j + half), &o0, &o1);
    idx[j] = (int)(o0 & (uint32_t)mask);
  } else {
    tf2x32(k0, k1, (uint32_t)(j - half), (uint32_t)j, &o0, &o1);
    idx[j] = (int)(o1 & (uint32_t)mask);
  }
}

// ---------------- block reduce (256 threads, wave64) ----------------
__device__ inline float blk_reduce_sum(float v) {
  __shared__ float s[4];
  for (int o = 32; o > 0; o >>= 1) v += __shfl_down(v, o);
  int lane = threadIdx.x & 63, w = threadIdx.x >> 6;
  if (lane == 0) s[w] = v;
  __syncthreads();
  float r = s[0] + s[1] + s[2] + s[3];
  __syncthreads();
  return r;
}

// ---------------- embedding ----------------
__global__ void embed_kernel(const float* __restrict__ x, const float* __restrict__ W,
                             const float* __restrict__ bias, float* __restrict__ h) {
  size_t gid = (size_t)blockIdx.x * 256 + threadIdx.x;
  int o = (int)(gid & 511);
  size_t bl = gid >> 9;
  const float* xr = x + bl * 7;
  float acc = bias[o];
#pragma unroll
  for (int i = 0; i < 7; ++i) acc += xr[i] * W[i * 512 + o];
  h[gid] = acc;
}

// ---------------- cast kernels ----------------
__global__ void cast_bf16(const float* __restrict__ src, ushort_t* __restrict__ dst,
                          size_t n) {
  size_t i = ((size_t)blockIdx.x * 256 + threadIdx.x) * 4;
  if (i >= n) return;
  float4 v = *(const float4*)(src + i);
  ushort4 o;
  o.x = f2b(v.x); o.y = f2b(v.y); o.z = f2b(v.z); o.w = f2b(v.w);
  *(ushort4*)(dst + i) = o;
}

// Bt[n*512+k] = bf16(W[k*512+n])   (512x512)
__global__ void castT512(const float* __restrict__ W, ushort_t* __restrict__ Bt) {
  int gid = blockIdx.x * 256 + threadIdx.x;
  int n = gid >> 9, k = gid & 511;
  Bt[gid] = f2b(W[(size_t)k * 512 + n]);
}

// Bt[n*1536 + dt*512 + i] = bf16(convW[n][i][dt])
__global__ void cast_convW(const float* __restrict__ W, ushort_t* __restrict__ Bt) {
  int gid = blockIdx.x * 256 + threadIdx.x;
  int n = gid / 1536, k = gid - n * 1536;
  int dt = k >> 9, ii = k & 511;
  Bt[gid] = f2b(W[((size_t)n * 512 + ii) * 3 + dt]);
}

// ---------------- bf16 MFMA GEMM (m97 structure) ----------------
// C(M,N) = A(M,K) @ Bt^T + bias.  A:[M][K] bf16, Bt:[N][K] bf16.
// grid = (N/128, M/128), 256 threads (4 waves, 2x2 over 128x128 tile).
// CONVMODE: A rows are circular taps of a [CB*L][512] buffer, K = 3*512.
// EPI: 0 = store bf16 (QKV)          1 = f32 accumulate (Wo, FF2)
//      2 = exact GELU -> bf16 (FF1)  3 = BN+ELU -> f32 (conv)
__device__ __forceinline__ float gelu_exact(float c) {
  return 0.5f * c * (1.0f + erff(c * 0.70710678118654752f));
}

template <int CONVMODE, int EPI>
__global__ __launch_bounds__(256) void mfma_gemm(
    const ushort_t* __restrict__ A, const ushort_t* __restrict__ Bt,
    const float* __restrict__ bias, float* __restrict__ Cf,
    ushort_t* __restrict__ Cb, const float* __restrict__ bng,
    const float* __restrict__ bnb, int N, int K, int L) {
  __shared__ __align__(16) ushort_t As[128 * 64];
  __shared__ __align__(16) ushort_t Bs[128 * 64];
  const int tid = threadIdx.x;
  const int lane = tid & 63;
  const int wid = tid >> 6;
  const int wr = wid >> 1, wc = wid & 1;
  const int bm = blockIdx.y, bn = blockIdx.x;
  const int ln = lane & 15, lh = lane >> 4;

  f32x4 acc[4][4] = {};

  for (int k0 = 0; k0 < K; k0 += 64) {
    __syncthreads();
#pragma unroll
    for (int it = 0; it < 4; ++it) {
      int c = it * 256 + tid;
      int row = c >> 3, kc = (c & 7) * 8;
      size_t ga;
      if (CONVMODE) {
        int m = bm * 128 + row;
        int b = m / L, tpos = m - b * L;
        int k = k0 + kc;
        int dt = k >> 9, ii = k & 511;
        int tr2 = tpos + dt - 1;
        if (tr2 < 0) tr2 += L;
        if (tr2 >= L) tr2 -= L;
        ga = ((size_t)(b * L + tr2)) * 512 + ii;
      } else {
        ga = (size_t)(bm * 128 + row) * K + k0 + kc;
      }
      __builtin_amdgcn_global_load_lds(
          (const __attribute__((address_space(1))) void*)(A + ga),
          (__attribute__((address_space(3))) void*)(As + c * 8), 16, 0, 0);
      size_t gb = (size_t)(bn * 128 + row) * K + k0 + kc;
      __builtin_amdgcn_global_load_lds(
          (const __attribute__((address_space(1))) void*)(Bt + gb),
          (__attribute__((address_space(3))) void*)(Bs + c * 8), 16, 0, 0);
    }
    __syncthreads();
#pragma unroll
    for (int kk = 0; kk < 2; ++kk) {
      bf16x8 af[4], bf_[4];
#pragma unroll
      for (int m = 0; m < 4; ++m)
        af[m] = *(const bf16x8*)&As[(wr * 64 + m * 16 + ln) * 64 + kk * 32 + lh * 8];
#pragma unroll
      for (int n = 0; n < 4; ++n)
        bf_[n] = *(const bf16x8*)&Bs[(wc * 64 + n * 16 + ln) * 64 + kk * 32 + lh * 8];
#pragma unroll
      for (int m = 0; m < 4; ++m)
#pragma unroll
        for (int n = 0; n < 4; ++n)
          acc[m][n] =
              __builtin_amdgcn_mfma_f32_16x16x32_bf16(af[m], bf_[n], acc[m][n], 0, 0, 0);
    }
  }

  const float bnscale = 0.9999950000374996f;  // 1/sqrt(1+1e-5)
#pragma unroll
  for (int m = 0; m < 4; ++m) {
    int row = bm * 128 + wr * 64 + m * 16 + lh * 4;
#pragma unroll
    for (int n = 0; n < 4; ++n) {
      int col = bn * 128 + wc * 64 + n * 16 + ln;
      float bsv = bias[col];
#pragma unroll
      for (int r = 0; r < 4; ++r) {
        float cval = acc[m][n][r] + bsv;
        size_t oi = (size_t)(row + r) * N + col;
        if (EPI == 0) {
          Cb[oi] = f2b(cval);
        } else if (EPI == 1) {
          Cf[oi] += cval;
        } else if (EPI == 2) {
          Cb[oi] = f2b(gelu_exact(cval));
        } else {
          float c2 = cval * bnscale * bng[col] + bnb[col];
          Cf[oi] = c2 > 0.0f ? c2 : expm1f(c2);
        }
      }
    }
  }
}

// ---------------- LN (in-place, row = 512) ----------------
__global__ __launch_bounds__(256) void ln_inplace(float* __restrict__ h,
                                                  const float* __restrict__ g,
                                                  const float* __restrict__ b) {
  size_t row = blockIdx.x;
  float* hr = h + row * 512;
  int t = threadIdx.x;
  float x0 = hr[t], x1 = hr[t + 256];
  float mean = blk_reduce_sum(x0 + x1) * (1.0f / 512.0f);
  float d0 = x0 - mean, d1 = x1 - mean;
  float var = blk_reduce_sum(d0 * d0 + d1 * d1) * (1.0f / 512.0f);
  float rstd = rsqrtf(var + 1e-5f);
  hr[t] = d0 * rstd * g[t] + b[t];
  hr[t + 256] = d1 * rstd * g[t + 256] + b[t + 256];
}

// ---------------- prob-sparse M scores (bf16 q,k) ----------------
__global__ __launch_bounds__(256) void prob_scores(const ushort_t* __restrict__ q,
                                                   const ushort_t* __restrict__ k,
                                                   const int* __restrict__ idx,
                                                   float* __restrict__ Mout,
                                                   int L, int S) {
  int gid = blockIdx.x * 256 + threadIdx.x;  // over CB*H*L
  int l = gid % L;
  int bh = gid / L;
  int hh = bh & 7;
  int b = bh >> 3;
  const ushort_t* qr = q + ((size_t)(b * L + l)) * 512 + hh * 64;
  float qq[64];
#pragma unroll
  for (int c = 0; c < 8; ++c) {
    uint4 u = ((const uint4*)qr)[c];
    qq[c * 8 + 0] = b2f_lo(u.x); qq[c * 8 + 1] = b2f_hi(u.x);
    qq[c * 8 + 2] = b2f_lo(u.y); qq[c * 8 + 3] = b2f_hi(u.y);
    qq[c * 8 + 4] = b2f_lo(u.z); qq[c * 8 + 5] = b2f_hi(u.z);
    qq[c * 8 + 6] = b2f_lo(u.w); qq[c * 8 + 7] = b2f_hi(u.w);
  }
  float m = -INFINITY, ssum = 0.0f;
  for (int s = 0; s < S; ++s) {
    int j = idx[l * S + s];
    const ushort_t* kr = k + ((size_t)(b * L + j)) * 512 + hh * 64;
    float dot = 0.0f;
#pragma unroll
    for (int c = 0; c < 8; ++c) {
      uint4 u = ((const uint4*)kr)[c];
      dot += qq[c * 8 + 0] * b2f_lo(u.x) + qq[c * 8 + 1] * b2f_hi(u.x) +
             qq[c * 8 + 2] * b2f_lo(u.y) + qq[c * 8 + 3] * b2f_hi(u.y) +
             qq[c * 8 + 4] * b2f_lo(u.z) + qq[c * 8 + 5] * b2f_hi(u.z) +
             qq[c * 8 + 6] * b2f_lo(u.w) + qq[c * 8 + 7] * b2f_hi(u.w);
    }
    m = fmaxf(m, dot);
    ssum += dot;
  }
  Mout[(size_t)bh * L + l] = m - ssum / (float)L;
}

// ---------------- top-k (iterative argmax, lower index wins ties) ----------------
__global__ __launch_bounds__(256) void topk_kernel(const float* __restrict__ Mbuf,
                                                   int* __restrict__ top_idx,
                                                   int L, int S) {
  int bh = blockIdx.x;
  __shared__ float vals[4096];
  __shared__ float rv[256];
  __shared__ int ri[256];
  const float* Mr = Mbuf + (size_t)bh * L;
  int t = threadIdx.x;
  for (int j = t; j < L; j += 256) vals[j] = Mr[j];
  __syncthreads();
  for (int it = 0; it < S; ++it) {
    float bv = -INFINITY;
    int bi = L;
    for (int j = t; j < L; j += 256) {
      float v = vals[j];
      if (v > bv || (v == bv && j < bi)) { bv = v; bi = j; }
    }
    rv[t] = bv; ri[t] = bi;
    __syncthreads();
    for (int s2 = 128; s2 > 0; s2 >>= 1) {
      if (t < s2) {
        float ov = rv[t + s2]; int oi = ri[t + s2];
        if (ov > rv[t] || (ov == rv[t] && oi < ri[t])) { rv[t] = ov; ri[t] = oi; }
      }
      __syncthreads();
    }
    if (t == 0) {
      top_idx[bh * S + it] = ri[0];
      vals[ri[0]] = -INFINITY;
    }
    __syncthreads();
  }
}

// ---------------- mean of V over sequence (bf16 v) ----------------
__global__ __launch_bounds__(256) void mean_v_kernel(const ushort_t* __restrict__ v,
                                                     float* __restrict__ mv, int L) {
  int bh = blockIdx.x;
  int b = bh >> 3, hh = bh & 7;
  int t = threadIdx.x;
  int d = t & 63, p = t >> 6;
  float acc = 0.0f;
  for (int j = p; j < L; j += 4)
    acc += bu2f(v[((size_t)(b * L + j)) * 512 + hh * 64 + d]);
  __shared__ float part[4][64];
  part[p][d] = acc;
  __syncthreads();
  if (p == 0)
    mv[bh * 64 + d] = (part[0][d] + part[1][d] + part[2][d] + part[3][d]) / (float)L;
}

// ---------------- fill ctx (bf16) with broadcast mean ----------------
__global__ void fill_ctx(ushort_t* __restrict__ ctx, const float* __restrict__ mv,
                         int L) {
  size_t gid = (size_t)blockIdx.x * 256 + threadIdx.x;  // CB*L*512
  int c = (int)(gid & 511);
  size_t bl = gid >> 9;
  int b = (int)(bl / (size_t)L);
  ctx[gid] = f2b(mv[(b * 8 + (c >> 6)) * 64 + (c & 63)]);
}

// ---------------- full attention for selected queries (bf16 q,k,v,ctx) ----------------
__global__ __launch_bounds__(256) void attn_update(const ushort_t* __restrict__ q,
                                                   const ushort_t* __restrict__ k,
                                                   const ushort_t* __restrict__ v,
                                                   const int* __restrict__ top_idx,
                                                   ushort_t* __restrict__ ctx,
                                                   int L, int S) {
  __shared__ float qs[64];
  __shared__ float sc[4096];
  __shared__ float red[256];
  __shared__ float part[4][64];
  int blk = blockIdx.x;
  int u = blk % S;
  int bh = blk / S;
  int hh = bh & 7, b = bh >> 3;
  int t = threadIdx.x;
  int l = top_idx[bh * S + u];
  if (t < 64) qs[t] = bu2f(q[((size_t)(b * L + l)) * 512 + hh * 64 + t]);
  __syncthreads();
  float lmax = -INFINITY;
  for (int j = t; j < L; j += 256) {
    const ushort_t* kr = k + ((size_t)(b * L + j)) * 512 + hh * 64;
    float dot = 0.0f;
#pragma unroll
    for (int c = 0; c < 8; ++c) {
      uint4 uu = ((const uint4*)kr)[c];
      dot += qs[c * 8 + 0] * b2f_lo(uu.x) + qs[c * 8 + 1] * b2f_hi(uu.x) +
             qs[c * 8 + 2] * b2f_lo(uu.y) + qs[c * 8 + 3] * b2f_hi(uu.y) +
             qs[c * 8 + 4] * b2f_lo(uu.z) + qs[c * 8 + 5] * b2f_hi(uu.z) +
             qs[c * 8 + 6] * b2f_lo(uu.w) + qs[c * 8 + 7] * b2f_hi(uu.w);
    }
    dot *= 0.125f;  // 1/sqrt(64)
    sc[j] = dot;
    lmax = fmaxf(lmax, dot);
  }
  red[t] = lmax;
  __syncthreads();
  for (int s2 = 128; s2 > 0; s2 >>= 1) {
    if (t < s2) red[t] = fmaxf(red[t], red[t + s2]);
    __syncthreads();
  }
  float m = red[0];
  __syncthreads();
  float lsum = 0.0f;
  for (int j = t; j < L; j += 256) {
    float e = expf(sc[j] - m);
    sc[j] = e;
    lsum += e;
  }
  red[t] = lsum;
  __syncthreads();
  for (int s2 = 128; s2 > 0; s2 >>= 1) {
    if (t < s2) red[t] += red[t + s2];
    __syncthreads();
  }
  float Z = red[0];
  __syncthreads();
  int d = t & 63, p = t >> 6;
  float acc = 0.0f;
  for (int j = p; j < L; j += 4)
    acc += sc[j] * bu2f(v[((size_t)(b * L + j)) * 512 + hh * 64 + d]);
  part[p][d] = acc;
  __syncthreads();
  if (p == 0)
    ctx[((size_t)(b * L + l)) * 512 + hh * 64 + d] =
        f2b((part[0][d] + part[1][d] + part[2][d] + part[3][d]) / Z);
}

// ---------------- maxpool window 3 stride 2 ----------------
__global__ void maxpool_kernel(const float* __restrict__ y, float* __restrict__ hout,
                               int L) {
  size_t gid = (size_t)blockIdx.x * 256 + threadIdx.x;  // CB*(L/2)*512
  int Lh = L >> 1;
  int o = (int)(gid & 511);
  size_t bj = gid >> 9;
  int j = (int)(bj % (size_t)Lh);
  int b = (int)(bj / (size_t)Lh);
  const float* base = y + ((size_t)(b * L + 2 * j)) * 512 + o;
  float mx = base[0];
  if (j > 0) mx = fmaxf(mx, base[-512]);
  mx = fmaxf(mx, base[512]);
  hout[gid] = mx;
}

// ---------------- final LN + projection ----------------
__global__ __launch_bounds__(256) void final_ln_proj(const float* __restrict__ h,
                                                     const float* __restrict__ g,
                                                     const float* __restrict__ bb,
                                                     const float* __restrict__ pw,
                                                     const float* __restrict__ pb,
                                                     float* __restrict__ out, int L) {
  int b = blockIdx.x / 47, l = blockIdx.x % 47;
  const float* hr = h + ((size_t)(b * L + l)) * 512;
  int t = threadIdx.x;
  float x0 = hr[t], x1 = hr[t + 256];
  float mean = blk_reduce_sum(x0 + x1) * (1.0f / 512.0f);
  float d0 = x0 - mean, d1 = x1 - mean;
  float var = blk_reduce_sum(d0 * d0 + d1 * d1) * (1.0f / 512.0f);
  float rstd = rsqrtf(var + 1e-5f);
  float y0 = d0 * rstd * g[t] + bb[t];
  float y1 = d1 * rstd * g[t + 256] + bb[t + 256];
  float dot = blk_reduce_sum(y0 * pw[t] + y1 * pw[t + 256]);
  if (t == 0) out[b * 47 + l] = dot + pb[0];
}

// ---------------- launcher ----------------
extern "C" void kernel_launch(void* const* d_in, const int* in_sizes, int n_in,
                              void* d_out, int out_size, void* d_ws, size_t ws_size,
                              hipStream_t stream) {
  const float* x = (const float*)d_in[0];
  const float* emb_W = (const float*)d_in[1];
  const float* emb_b = (const float*)d_in[2];
  const float* Wq = (const float*)d_in[3];
  const float* bq = (const float*)d_in[4];
  const float* Wk = (const float*)d_in[5];
  const float* bk = (const float*)d_in[6];
  const float* Wv = (const float*)d_in[7];
  const float* bv = (const float*)d_in[8];
  const float* Wo = (const float*)d_in[9];
  const float* bo = (const float*)d_in[10];
  const float* fW1 = (const float*)d_in[11];
  const float* fb1 = (const float*)d_in[12];
  const float* fW2 = (const float*)d_in[13];
  const float* fb2 = (const float*)d_in[14];
  const float* ln1g = (const float*)d_in[15];
  const float* ln1b = (const float*)d_in[16];
  const float* ln2g = (const float*)d_in[17];
  const float* ln2b = (const float*)d_in[18];
  const float* cW = (const float*)d_in[19];
  const float* cb = (const float*)d_in[20];
  const float* bng = (const float*)d_in[21];
  const float* bnb = (const float*)d_in[22];
  const float* flng = (const float*)d_in[23];
  const float* flnb = (const float*)d_in[24];
  const float* pW = (const float*)d_in[25];
  const float* pb = (const float*)d_in[26];
  float* out = (float*)d_out;

  // batch-group size from ws_size
  int CB = 4;
  while (CB > 1) {
    size_t cbseg = (size_t)CB * 2097152ull;
    size_t need = 33554432ull + 1966080ull + (5ull * cbseg) / 2 +
                  (size_t)CB * 32768 + (size_t)CB * 512 + (size_t)CB * 384 +
                  196608ull + 1024ull;
    if (need * 4 <= ws_size) break;
    CB >>= 1;
  }
  const size_t CBseg = (size_t)CB * 2097152ull;  // CB*4096*512

  float* ws = (float*)d_ws;
  size_t off = 0;
  float* h = ws;                          off += 33554432ull;
  ushort_t* wbase = (ushort_t*)(ws + off); off += 1966080ull;
  ushort_t* WqT = wbase;
  ushort_t* WkT = wbase + 262144;
  ushort_t* WvT = wbase + 524288;
  ushort_t* WoT = wbase + 786432;
  ushort_t* W1b = wbase + 1048576;
  ushort_t* W2b = wbase + 2097152;
  ushort_t* Wcb = wbase + 3145728;
  ushort_t* gArea = (ushort_t*)(ws + off); off += (5ull * CBseg) / 2;
  ushort_t* hb = gArea;
  ushort_t* qb = gArea + CBseg;
  ushort_t* kbuf = gArea + 2 * CBseg;
  ushort_t* vb = gArea + 3 * CBseg;
  ushort_t* ctxb = gArea + 4 * CBseg;
  ushort_t* ybuf = qb;           // spans qb..ctxb (4*CBseg bf16)
  float* convY = (float*)qb;     // spans qb,kbuf (CBseg f32)
  float* Mbuf = ws + off;                 off += (size_t)CB * 32768;
  float* mv = ws + off;                   off += (size_t)CB * 512;
  int* topidx = (int*)(ws + off);         off += (size_t)CB * 384;
  int* idxbuf = (int*)(ws + off);         off += 196608ull;

  // embedding
  {
    size_t total = (size_t)NB * 4096 * DM;
    embed_kernel<<<(int)(total / 256), 256, 0, stream>>>(x, emb_W, emb_b, h);
  }

  int L = 4096;
  for (int i = 0; i < 3; ++i) {
    int S = (i == 0) ? 45 : (i == 1) ? 40 : 35;
    int ngroups = NB / CB;
    int Mg = CB * L;
    size_t segL = (size_t)Mg * 512;

    // per-layer weight casts
    castT512<<<1024, 256, 0, stream>>>(Wq + (size_t)i * 262144, WqT);
    castT512<<<1024, 256, 0, stream>>>(Wk + (size_t)i * 262144, WkT);
    castT512<<<1024, 256, 0, stream>>>(Wv + (size_t)i * 262144, WvT);
    castT512<<<1024, 256, 0, stream>>>(Wo + (size_t)i * 262144, WoT);
    cast_bf16<<<1024, 256, 0, stream>>>(fW1 + (size_t)i * 1048576, W1b, 1048576);
    cast_bf16<<<1024, 256, 0, stream>>>(fW2 + (size_t)i * 1048576, W2b, 1048576);
    if (i < 2) cast_convW<<<3072, 256, 0, stream>>>(cW + (size_t)i * 786432, Wcb);

    // JAX randint key
    uint32_t fa, fbk;
    tf2x32(0u, 42u, 0u, (uint32_t)i, &fa, &fbk);
    uint32_t a0, b0, a1, b1;
    tf2x32(fa, fbk, 0u, 2u, &a0, &b0);
    tf2x32(fa, fbk, 1u, 3u, &a1, &b1);
    int n = L * S;
    gen_idx_kernel<<<(n + 255) / 256, 256, 0, stream>>>(idxbuf, b0, b1, n, L - 1);

    // ---- attention per batch group ----
    for (int g = 0; g < ngroups; ++g) {
      float* hg = h + (size_t)g * segL;
      cast_bf16<<<(int)(segL / 1024), 256, 0, stream>>>(hg, hb, segL);
      dim3 gq(4, Mg / 128);
      mfma_gemm<0, 0><<<gq, 256, 0, stream>>>(hb, WqT, bq + i * DM, nullptr, qb,
                                              nullptr, nullptr, 512, 512, 0);
      mfma_gemm<0, 0><<<gq, 256, 0, stream>>>(hb, WkT, bk + i * DM, nullptr, kbuf,
                                              nullptr, nullptr, 512, 512, 0);
      mfma_gemm<0, 0><<<gq, 256, 0, stream>>>(hb, WvT, bv + i * DM, nullptr, vb,
                                              nullptr, nullptr, 512, 512, 0);

      prob_scores<<<(CB * NH * L) / 256, 256, 0, stream>>>(qb, kbuf, idxbuf, Mbuf, L, S);
      topk_kernel<<<CB * NH, 256, 0, stream>>>(Mbuf, topidx, L, S);
      mean_v_kernel<<<CB * NH, 256, 0, stream>>>(vb, mv, L);
      fill_ctx<<<(int)(segL / 256), 256, 0, stream>>>(ctxb, mv, L);
      attn_update<<<CB * NH * S, 256, 0, stream>>>(qb, kbuf, vb, topidx, ctxb, L, S);

      mfma_gemm<0, 1><<<gq, 256, 0, stream>>>(ctxb, WoT, bo + i * DM, hg, nullptr,
                                              nullptr, nullptr, 512, 512, 0);
    }
    ln_inplace<<<NB * L, 256, 0, stream>>>(h, ln1g + i * DM, ln1b + i * DM);

    // ---- FF row-chunked ----
    int rows = NB * L;
    int R = CB * 4096;
    for (int r0 = 0; r0 < rows; r0 += R) {
      float* hr = h + (size_t)r0 * 512;
      cast_bf16<<<(int)(CBseg / 1024), 256, 0, stream>>>(hr, hb, CBseg);
      dim3 g1(16, R / 128);
      mfma_gemm<0, 2><<<g1, 256, 0, stream>>>(hb, W1b, fb1 + i * DFF_, nullptr, ybuf,
                                              nullptr, nullptr, 2048, 512, 0);
      dim3 g2(4, R / 128);
      mfma_gemm<0, 1><<<g2, 256, 0, stream>>>(ybuf, W2b, fb2 + i * DM, hr, nullptr,
                                              nullptr, nullptr, 512, 2048, 0);
    }
    ln_inplace<<<NB * L, 256, 0, stream>>>(h, ln2g + i * DM, ln2b + i * DM);

    // ---- conv + maxpool per batch group ----
    if (i < 2) {
      int Lh = L / 2;
      for (int g = 0; g < ngroups; ++g) {
        float* hg = h + (size_t)g * segL;
        cast_bf16<<<(int)(segL / 1024), 256, 0, stream>>>(hg, hb, segL);
        dim3 gc(4, Mg / 128);
        mfma_gemm<1, 3><<<gc, 256, 0, stream>>>(hb, Wcb, cb + i * DM, convY, nullptr,
                                                bng + i * DM, bnb + i * DM, 512, 1536, L);
        size_t tot = (size_t)CB * Lh * 512;
        maxpool_kernel<<<(int)(tot / 256), 256, 0, stream>>>(
            convY, h + (size_t)g * CB * Lh * 512, L);
      }
      L = Lh;
    }
  }

  final_ln_proj<<<NB * 47, 256, 0, stream>>>(h, flng, flnb, pW, pb, out, L);
}

// Round 4
// 8072.970 us; speedup vs baseline: 4.0950x; 1.2663x over previous
//
#include <hip/hip_runtime.h>
#include <cstdint>
#include <math.h>

#define NB 16
#define DM 512
#define NH 8
#define DFF_ 2048
#define SMAX 45
#define PVJ 8

typedef unsigned short ushort_t;
typedef __bf16 bf16x8 __attribute__((ext_vector_type(8)));
typedef float f32x4 __attribute__((ext_vector_type(4)));

// ---------------- bf16 helpers ----------------
__device__ __forceinline__ ushort_t f2b(float f) {  // RNE f32 -> bf16 bits
  uint32_t u = __float_as_uint(f);
  uint32_t r = (u + 0x7FFFu + ((u >> 16) & 1u)) >> 16;
  return (ushort_t)r;
}
__device__ __forceinline__ float bu2f(ushort_t x) {
  return __uint_as_float((uint32_t)x << 16);
}
__device__ __forceinline__ float b2f_lo(uint32_t u) { return __uint_as_float(u << 16); }
__device__ __forceinline__ float b2f_hi(uint32_t u) { return __uint_as_float(u & 0xFFFF0000u); }

// ---------------- threefry2x32 (JAX-compatible) ----------------
__host__ __device__ inline void tf2x32(uint32_t k0, uint32_t k1,
                                       uint32_t x0, uint32_t x1,
                                       uint32_t* o0, uint32_t* o1) {
  uint32_t ks0 = k0, ks1 = k1, ks2 = k0 ^ k1 ^ 0x1BD11BDAu;
  x0 += ks0; x1 += ks1;
#define TF_RND(r) { x0 += x1; x1 = (x1 << (r)) | (x1 >> (32 - (r))); x1 ^= x0; }
  TF_RND(13) TF_RND(15) TF_RND(26) TF_RND(6)
  x0 += ks1; x1 += ks2 + 1u;
  TF_RND(17) TF_RND(29) TF_RND(16) TF_RND(24)
  x0 += ks2; x1 += ks0 + 2u;
  TF_RND(13) TF_RND(15) TF_RND(26) TF_RND(6)
  x0 += ks0; x1 += ks1 + 3u;
  TF_RND(17) TF_RND(29) TF_RND(16) TF_RND(24)
  x0 += ks1; x1 += ks2 + 4u;
  TF_RND(13) TF_RND(15) TF_RND(26) TF_RND(6)
  x0 += ks2; x1 += ks0 + 5u;
#undef TF_RND
  *o0 = x0; *o1 = x1;
}

__global__ void gen_idx_kernel(int* __restrict__ idx, uint32_t k0, uint32_t k1,
                               int n, int mask) {
  int j = blockIdx.x * 256 + threadIdx.x;
  if (j >= n) return;
  int half = n >> 1;
  uint32_t o0, o1;
  if (j < half) {
    tf2x32(k0, k1, (uint32_t)j, (uint32_t)(j + half), &o0, &o1);
    idx[j] = (int)(o0 & (uint32_t)mask);
  } else {
    tf2x32(k0, k1, (uint32_t)(j - half), (uint32_t)j, &o0, &o1);
    idx[j] = (int)(o1 & (uint32_t)mask);
  }
}

// ---------------- block reduce helpers (256 threads, wave64) ----------------
__device__ inline float blk_reduce_sum(float v) {
  __shared__ float s[4];
  for (int o = 32; o > 0; o >>= 1) v += __shfl_down(v, o);
  int lane = threadIdx.x & 63, w = threadIdx.x >> 6;
  if (lane == 0) s[w] = v;
  __syncthreads();
  float r = s[0] + s[1] + s[2] + s[3];
  __syncthreads();
  return r;
}
__device__ inline float blk_reduce_max(float v) {
  __shared__ float s[4];
  for (int o = 32; o > 0; o >>= 1) v = fmaxf(v, __shfl_down(v, o));
  int lane = threadIdx.x & 63, w = threadIdx.x >> 6;
  if (lane == 0) s[w] = v;
  __syncthreads();
  float r = fmaxf(fmaxf(s[0], s[1]), fmaxf(s[2], s[3]));
  __syncthreads();
  return r;
}

// ---------------- embedding ----------------
__global__ void embed_kernel(const float* __restrict__ x, const float* __restrict__ W,
                             const float* __restrict__ bias, float* __restrict__ h) {
  size_t gid = (size_t)blockIdx.x * 256 + threadIdx.x;
  int o = (int)(gid & 511);
  size_t bl = gid >> 9;
  const float* xr = x + bl * 7;
  float acc = bias[o];
#pragma unroll
  for (int i = 0; i < 7; ++i) acc += xr[i] * W[i * 512 + o];
  h[gid] = acc;
}

// ---------------- cast kernels ----------------
__global__ void cast_bf16(const float* __restrict__ src, ushort_t* __restrict__ dst,
                          size_t n) {
  size_t i = ((size_t)blockIdx.x * 256 + threadIdx.x) * 4;
  if (i >= n) return;
  float4 v = *(const float4*)(src + i);
  ushort4 o;
  o.x = f2b(v.x); o.y = f2b(v.y); o.z = f2b(v.z); o.w = f2b(v.w);
  *(ushort4*)(dst + i) = o;
}

// Bt[n*512+k] = bf16(W[k*512+n])   (512x512)
__global__ void castT512(const float* __restrict__ W, ushort_t* __restrict__ Bt) {
  int gid = blockIdx.x * 256 + threadIdx.x;
  int n = gid >> 9, k = gid & 511;
  Bt[gid] = f2b(W[(size_t)k * 512 + n]);
}

// Bt[n*1536 + dt*512 + i] = bf16(convW[n][i][dt])
__global__ void cast_convW(const float* __restrict__ W, ushort_t* __restrict__ Bt) {
  int gid = blockIdx.x * 256 + threadIdx.x;
  int n = gid / 1536, k = gid - n * 1536;
  int dt = k >> 9, ii = k & 511;
  Bt[gid] = f2b(W[((size_t)n * 512 + ii) * 3 + dt]);
}

// ---------------- bf16 MFMA GEMM (m97 structure) ----------------
__device__ __forceinline__ float gelu_exact(float c) {
  return 0.5f * c * (1.0f + erff(c * 0.70710678118654752f));
}

template <int CONVMODE, int EPI>
__global__ __launch_bounds__(256) void mfma_gemm(
    const ushort_t* __restrict__ A, const ushort_t* __restrict__ Bt,
    const float* __restrict__ bias, float* __restrict__ Cf,
    ushort_t* __restrict__ Cb, const float* __restrict__ bng,
    const float* __restrict__ bnb, int N, int K, int L) {
  __shared__ __align__(16) ushort_t As[128 * 64];
  __shared__ __align__(16) ushort_t Bs[128 * 64];
  const int tid = threadIdx.x;
  const int lane = tid & 63;
  const int wid = tid >> 6;
  const int wr = wid >> 1, wc = wid & 1;
  const int bm = blockIdx.y, bn = blockIdx.x;
  const int ln = lane & 15, lh = lane >> 4;

  f32x4 acc[4][4] = {};

  for (int k0 = 0; k0 < K; k0 += 64) {
    __syncthreads();
#pragma unroll
    for (int it = 0; it < 4; ++it) {
      int c = it * 256 + tid;
      int row = c >> 3, kc = (c & 7) * 8;
      size_t ga;
      if (CONVMODE) {
        int m = bm * 128 + row;
        int b = m / L, tpos = m - b * L;
        int k = k0 + kc;
        int dt = k >> 9, ii = k & 511;
        int tr2 = tpos + dt - 1;
        if (tr2 < 0) tr2 += L;
        if (tr2 >= L) tr2 -= L;
        ga = ((size_t)(b * L + tr2)) * 512 + ii;
      } else {
        ga = (size_t)(bm * 128 + row) * K + k0 + kc;
      }
      __builtin_amdgcn_global_load_lds(
          (const __attribute__((address_space(1))) void*)(A + ga),
          (__attribute__((address_space(3))) void*)(As + c * 8), 16, 0, 0);
      size_t gb = (size_t)(bn * 128 + row) * K + k0 + kc;
      __builtin_amdgcn_global_load_lds(
          (const __attribute__((address_space(1))) void*)(Bt + gb),
          (__attribute__((address_space(3))) void*)(Bs + c * 8), 16, 0, 0);
    }
    __syncthreads();
#pragma unroll
    for (int kk = 0; kk < 2; ++kk) {
      bf16x8 af[4], bf_[4];
#pragma unroll
      for (int m = 0; m < 4; ++m)
        af[m] = *(const bf16x8*)&As[(wr * 64 + m * 16 + ln) * 64 + kk * 32 + lh * 8];
#pragma unroll
      for (int n = 0; n < 4; ++n)
        bf_[n] = *(const bf16x8*)&Bs[(wc * 64 + n * 16 + ln) * 64 + kk * 32 + lh * 8];
#pragma unroll
      for (int m = 0; m < 4; ++m)
#pragma unroll
        for (int n = 0; n < 4; ++n)
          acc[m][n] =
              __builtin_amdgcn_mfma_f32_16x16x32_bf16(af[m], bf_[n], acc[m][n], 0, 0, 0);
    }
  }

  const float bnscale = 0.9999950000374996f;  // 1/sqrt(1+1e-5)
#pragma unroll
  for (int m = 0; m < 4; ++m) {
    int row = bm * 128 + wr * 64 + m * 16 + lh * 4;
#pragma unroll
    for (int n = 0; n < 4; ++n) {
      int col = bn * 128 + wc * 64 + n * 16 + ln;
      float bsv = bias[col];
#pragma unroll
      for (int r = 0; r < 4; ++r) {
        float cval = acc[m][n][r] + bsv;
        size_t oi = (size_t)(row + r) * N + col;
        if (EPI == 0) {
          Cb[oi] = f2b(cval);
        } else if (EPI == 1) {
          Cf[oi] += cval;
        } else if (EPI == 2) {
          Cb[oi] = f2b(gelu_exact(cval));
        } else {
          float c2 = cval * bnscale * bng[col] + bnb[col];
          Cf[oi] = c2 > 0.0f ? c2 : expm1f(c2);
        }
      }
    }
  }
}

// ---------------- LN (in-place, row = 512) ----------------
__global__ __launch_bounds__(256) void ln_inplace(float* __restrict__ h,
                                                  const float* __restrict__ g,
                                                  const float* __restrict__ b) {
  size_t row = blockIdx.x;
  float* hr = h + row * 512;
  int t = threadIdx.x;
  float x0 = hr[t], x1 = hr[t + 256];
  float mean = blk_reduce_sum(x0 + x1) * (1.0f / 512.0f);
  float d0 = x0 - mean, d1 = x1 - mean;
  float var = blk_reduce_sum(d0 * d0 + d1 * d1) * (1.0f / 512.0f);
  float rstd = rsqrtf(var + 1e-5f);
  hr[t] = d0 * rstd * g[t] + b[t];
  hr[t + 256] = d1 * rstd * g[t + 256] + b[t + 256];
}

// ---------------- prob-sparse M scores (bf16 q,k) ----------------
__global__ __launch_bounds__(256) void prob_scores(const ushort_t* __restrict__ q,
                                                   const ushort_t* __restrict__ k,
                                                   const int* __restrict__ idx,
                                                   float* __restrict__ Mout,
                                                   int L, int S) {
  int gid = blockIdx.x * 256 + threadIdx.x;  // over CB*H*L
  int l = gid % L;
  int bh = gid / L;
  int hh = bh & 7;
  int b = bh >> 3;
  const ushort_t* qr = q + ((size_t)(b * L + l)) * 512 + hh * 64;
  float qq[64];
#pragma unroll
  for (int c = 0; c < 8; ++c) {
    uint4 u = ((const uint4*)qr)[c];
    qq[c * 8 + 0] = b2f_lo(u.x); qq[c * 8 + 1] = b2f_hi(u.x);
    qq[c * 8 + 2] = b2f_lo(u.y); qq[c * 8 + 3] = b2f_hi(u.y);
    qq[c * 8 + 4] = b2f_lo(u.z); qq[c * 8 + 5] = b2f_hi(u.z);
    qq[c * 8 + 6] = b2f_lo(u.w); qq[c * 8 + 7] = b2f_hi(u.w);
  }
  float m = -INFINITY, ssum = 0.0f;
  for (int s = 0; s < S; ++s) {
    int j = idx[l * S + s];
    const ushort_t* kr = k + ((size_t)(b * L + j)) * 512 + hh * 64;
    float dot = 0.0f;
#pragma unroll
    for (int c = 0; c < 8; ++c) {
      uint4 u = ((const uint4*)kr)[c];
      dot += qq[c * 8 + 0] * b2f_lo(u.x) + qq[c * 8 + 1] * b2f_hi(u.x) +
             qq[c * 8 + 2] * b2f_lo(u.y) + qq[c * 8 + 3] * b2f_hi(u.y) +
             qq[c * 8 + 4] * b2f_lo(u.z) + qq[c * 8 + 5] * b2f_hi(u.z) +
             qq[c * 8 + 6] * b2f_lo(u.w) + qq[c * 8 + 7] * b2f_hi(u.w);
    }
    m = fmaxf(m, dot);
    ssum += dot;
  }
  Mout[(size_t)bh * L + l] = m - ssum / (float)L;
}

// ---------------- top-k (iterative argmax, lower index wins ties) ----------------
__global__ __launch_bounds__(256) void topk_kernel(const float* __restrict__ Mbuf,
                                                   int* __restrict__ top_idx,
                                                   int L, int S) {
  int bh = blockIdx.x;
  __shared__ float vals[4096];
  __shared__ float rv[256];
  __shared__ int ri[256];
  const float* Mr = Mbuf + (size_t)bh * L;
  int t = threadIdx.x;
  for (int j = t; j < L; j += 256) vals[j] = Mr[j];
  __syncthreads();
  for (int it = 0; it < S; ++it) {
    float bv = -INFINITY;
    int bi = L;
    for (int j = t; j < L; j += 256) {
      float v = vals[j];
      if (v > bv || (v == bv && j < bi)) { bv = v; bi = j; }
    }
    rv[t] = bv; ri[t] = bi;
    __syncthreads();
    for (int s2 = 128; s2 > 0; s2 >>= 1) {
      if (t < s2) {
        float ov = rv[t + s2]; int oi = ri[t + s2];
        if (ov > rv[t] || (ov == rv[t] && oi < ri[t])) { rv[t] = ov; ri[t] = oi; }
      }
      __syncthreads();
    }
    if (t == 0) {
      top_idx[bh * S + it] = ri[0];
      vals[ri[0]] = -INFINITY;
    }
    __syncthreads();
  }
}

// ---------------- mean of V over sequence (bf16 v) ----------------
__global__ __launch_bounds__(256) void mean_v_kernel(const ushort_t* __restrict__ v,
                                                     float* __restrict__ mv, int L) {
  int bh = blockIdx.x;
  int b = bh >> 3, hh = bh & 7;
  int t = threadIdx.x;
  int d = t & 63, p = t >> 6;
  float acc = 0.0f;
  for (int j = p; j < L; j += 4)
    acc += bu2f(v[((size_t)(b * L + j)) * 512 + hh * 64 + d]);
  __shared__ float part[4][64];
  part[p][d] = acc;
  __syncthreads();
  if (p == 0)
    mv[bh * 64 + d] = (part[0][d] + part[1][d] + part[2][d] + part[3][d]) / (float)L;
}

// ---------------- fill ctx (bf16) with broadcast mean ----------------
__global__ void fill_ctx(ushort_t* __restrict__ ctx, const float* __restrict__ mv,
                         int L) {
  size_t gid = (size_t)blockIdx.x * 256 + threadIdx.x;  // CB*L*512
  int c = (int)(gid & 511);
  size_t bl = gid >> 9;
  int b = (int)(bl / (size_t)L);
  ctx[gid] = f2b(mv[(b * 8 + (c >> 6)) * 64 + (c & 63)]);
}

// ---------------- attention stage 1: scores for selected queries ----------------
// grid (L/256, CB*NH). sc[bh][u][j] = (q_red[u] . k[j]) / 8
__global__ __launch_bounds__(256) void qk_scores(const ushort_t* __restrict__ q,
                                                 const ushort_t* __restrict__ k,
                                                 const int* __restrict__ top_idx,
                                                 float* __restrict__ sc,
                                                 int L, int S) {
  __shared__ float qs[SMAX * 64];
  int bh = blockIdx.y;
  int hh = bh & 7, b = bh >> 3;
  int t = threadIdx.x;
  for (int e = t; e < S * 64; e += 256) {
    int u = e >> 6, d = e & 63;
    int l = top_idx[bh * S + u];
    qs[e] = bu2f(q[((size_t)(b * L + l)) * 512 + hh * 64 + d]);
  }
  __syncthreads();
  int j = blockIdx.x * 256 + t;
  const ushort_t* kr = k + ((size_t)(b * L + j)) * 512 + hh * 64;
  float kk[64];
#pragma unroll
  for (int c = 0; c < 8; ++c) {
    uint4 u4 = ((const uint4*)kr)[c];
    kk[c * 8 + 0] = b2f_lo(u4.x); kk[c * 8 + 1] = b2f_hi(u4.x);
    kk[c * 8 + 2] = b2f_lo(u4.y); kk[c * 8 + 3] = b2f_hi(u4.y);
    kk[c * 8 + 4] = b2f_lo(u4.z); kk[c * 8 + 5] = b2f_hi(u4.z);
    kk[c * 8 + 6] = b2f_lo(u4.w); kk[c * 8 + 7] = b2f_hi(u4.w);
  }
  float* srow = sc + (size_t)bh * S * L + j;
  for (int u = 0; u < S; ++u) {
    const float4* qu = (const float4*)(qs + u * 64);
    float dot = 0.0f;
#pragma unroll
    for (int c = 0; c < 16; ++c) {
      float4 qv = qu[c];
      dot += qv.x * kk[c * 4 + 0] + qv.y * kk[c * 4 + 1] +
             qv.z * kk[c * 4 + 2] + qv.w * kk[c * 4 + 3];
    }
    srow[(size_t)u * L] = dot * 0.125f;
  }
}

// ---------------- attention stage 2: softmax rows (write exp, store Z) ----------------
__global__ __launch_bounds__(256) void softmax_exp(float* __restrict__ sc,
                                                   float* __restrict__ Zbuf, int L) {
  size_t row = blockIdx.x;  // bh*S + u
  float* sr = sc + row * L;
  int t = threadIdx.x;
  float m = -INFINITY;
  for (int j = t; j < L; j += 256) m = fmaxf(m, sr[j]);
  m = blk_reduce_max(m);
  float s = 0.0f;
  for (int j = t; j < L; j += 256) {
    float e = __expf(sr[j] - m);
    sr[j] = e;
    s += e;
  }
  s = blk_reduce_sum(s);
  if (t == 0) Zbuf[row] = s;
}

// ---------------- attention stage 3: PV partial sums ----------------
// grid (PVJ, CB*NH). part[js][bh][u][d] = sum_{j in split} P[u][j]*V[j][d]
__global__ __launch_bounds__(256) void pv_partial(const float* __restrict__ sc,
                                                  const ushort_t* __restrict__ v,
                                                  float* __restrict__ part,
                                                  int L, int S, int CBNH) {
  __shared__ float scs[SMAX][64];
  int bh = blockIdx.y, js = blockIdx.x;
  int hh = bh & 7, b = bh >> 3;
  int t = threadIdx.x;
  int d = t & 63, ug = t >> 6;
  int jlen = L / PVJ;
  int j0 = js * jlen;
  float acc[12] = {};
  const float* scb = sc + (size_t)bh * S * L;
  for (int jc = 0; jc < jlen; jc += 64) {
    __syncthreads();
    for (int e = t; e < S * 64; e += 256) {
      int u = e >> 6, jj = e & 63;
      scs[u][jj] = scb[(size_t)u * L + j0 + jc + jj];
    }
    __syncthreads();
#pragma unroll 2
    for (int jb = 0; jb < 64; jb += 4) {
      float vv[4];
#pragma unroll
      for (int r = 0; r < 4; ++r)
        vv[r] = bu2f(v[((size_t)(b * L + j0 + jc + jb + r)) * 512 + hh * 64 + d]);
#pragma unroll
      for (int mi = 0; mi < 12; ++mi) {
        int u = ug + mi * 4;
        if (u < S) {
          float4 p4 = *(const float4*)&scs[u][jb];
          acc[mi] += p4.x * vv[0] + p4.y * vv[1] + p4.z * vv[2] + p4.w * vv[3];
        }
      }
    }
  }
  float* pb = part + ((size_t)js * CBNH + bh) * (SMAX * 64);
#pragma unroll
  for (int mi = 0; mi < 12; ++mi) {
    int u = ug + mi * 4;
    if (u < S) pb[u * 64 + d] = acc[mi];
  }
}

// ---------------- attention stage 4: combine partials, /Z, scatter ----------------
__global__ void pv_finish(const float* __restrict__ part, const float* __restrict__ Zbuf,
                          const int* __restrict__ top_idx, ushort_t* __restrict__ ctx,
                          int L, int S, int CBNH) {
  int gid = blockIdx.x * 256 + threadIdx.x;  // over CBNH*S*64
  if (gid >= CBNH * S * 64) return;
  int d = gid & 63;
  int r = gid >> 6;  // bh*S + u
  int u = r % S, bh = r / S;
  int hh = bh & 7, b = bh >> 3;
  float s = 0.0f;
#pragma unroll
  for (int js = 0; js < PVJ; ++js)
    s += part[((size_t)js * CBNH + bh) * (SMAX * 64) + u * 64 + d];
  int l = top_idx[bh * S + u];
  ctx[((size_t)(b * L + l)) * 512 + hh * 64 + d] = f2b(s / Zbuf[r]);
}

// ---------------- maxpool window 3 stride 2 ----------------
__global__ void maxpool_kernel(const float* __restrict__ y, float* __restrict__ hout,
                               int L) {
  size_t gid = (size_t)blockIdx.x * 256 + threadIdx.x;  // CB*(L/2)*512
  int Lh = L >> 1;
  int o = (int)(gid & 511);
  size_t bj = gid >> 9;
  int j = (int)(bj % (size_t)Lh);
  int b = (int)(bj / (size_t)Lh);
  const float* base = y + ((size_t)(b * L + 2 * j)) * 512 + o;
  float mx = base[0];
  if (j > 0) mx = fmaxf(mx, base[-512]);
  mx = fmaxf(mx, base[512]);
  hout[gid] = mx;
}

// ---------------- final LN + projection ----------------
__global__ __launch_bounds__(256) void final_ln_proj(const float* __restrict__ h,
                                                     const float* __restrict__ g,
                                                     const float* __restrict__ bb,
                                                     const float* __restrict__ pw,
                                                     const float* __restrict__ pb,
                                                     float* __restrict__ out, int L) {
  int b = blockIdx.x / 47, l = blockIdx.x % 47;
  const float* hr = h + ((size_t)(b * L + l)) * 512;
  int t = threadIdx.x;
  float x0 = hr[t], x1 = hr[t + 256];
  float mean = blk_reduce_sum(x0 + x1) * (1.0f / 512.0f);
  float d0 = x0 - mean, d1 = x1 - mean;
  float var = blk_reduce_sum(d0 * d0 + d1 * d1) * (1.0f / 512.0f);
  float rstd = rsqrtf(var + 1e-5f);
  float y0 = d0 * rstd * g[t] + bb[t];
  float y1 = d1 * rstd * g[t + 256] + bb[t + 256];
  float dot = blk_reduce_sum(y0 * pw[t] + y1 * pw[t + 256]);
  if (t == 0) out[b * 47 + l] = dot + pb[0];
}

// ---------------- launcher ----------------
extern "C" void kernel_launch(void* const* d_in, const int* in_sizes, int n_in,
                              void* d_out, int out_size, void* d_ws, size_t ws_size,
                              hipStream_t stream) {
  const float* x = (const float*)d_in[0];
  const float* emb_W = (const float*)d_in[1];
  const float* emb_b = (const float*)d_in[2];
  const float* Wq = (const float*)d_in[3];
  const float* bq = (const float*)d_in[4];
  const float* Wk = (const float*)d_in[5];
  const float* bk = (const float*)d_in[6];
  const float* Wv = (const float*)d_in[7];
  const float* bv = (const float*)d_in[8];
  const float* Wo = (const float*)d_in[9];
  const float* bo = (const float*)d_in[10];
  const float* fW1 = (const float*)d_in[11];
  const float* fb1 = (const float*)d_in[12];
  const float* fW2 = (const float*)d_in[13];
  const float* fb2 = (const float*)d_in[14];
  const float* ln1g = (const float*)d_in[15];
  const float* ln1b = (const float*)d_in[16];
  const float* ln2g = (const float*)d_in[17];
  const float* ln2b = (const float*)d_in[18];
  const float* cW = (const float*)d_in[19];
  const float* cb = (const float*)d_in[20];
  const float* bng = (const float*)d_in[21];
  const float* bnb = (const float*)d_in[22];
  const float* flng = (const float*)d_in[23];
  const float* flnb = (const float*)d_in[24];
  const float* pW = (const float*)d_in[25];
  const float* pb = (const float*)d_in[26];
  float* out = (float*)d_out;

  // batch-group size from ws_size
  int CB = 4;
  while (CB > 1) {
    size_t need = 33554432ull + 1966080ull +
                  (size_t)CB * (5242880ull + 32768ull + 512ull + 384ull +
                                1474560ull + 360ull + 184320ull) +
                  196608ull + 2048ull;
    if (need * 4 <= ws_size) break;
    CB >>= 1;
  }
  const size_t CBseg = (size_t)CB * 2097152ull;  // CB*4096*512 (bf16 elems)
  const int CBNH = CB * NH;

  float* ws = (float*)d_ws;
  size_t off = 0;
  float* h = ws;                           off += 33554432ull;
  ushort_t* wbase = (ushort_t*)(ws + off); off += 1966080ull;
  ushort_t* WqT = wbase;
  ushort_t* WkT = wbase + 262144;
  ushort_t* WvT = wbase + 524288;
  ushort_t* WoT = wbase + 786432;
  ushort_t* W1b = wbase + 1048576;
  ushort_t* W2b = wbase + 2097152;
  ushort_t* Wcb = wbase + 3145728;
  ushort_t* gArea = (ushort_t*)(ws + off); off += (5ull * CBseg) / 2;
  ushort_t* hb = gArea;
  ushort_t* qb = gArea + CBseg;
  ushort_t* kbuf = gArea + 2 * CBseg;
  ushort_t* vb = gArea + 3 * CBseg;
  ushort_t* ctxb = gArea + 4 * CBseg;
  ushort_t* ybuf = qb;           // spans qb..ctxb (4*CBseg bf16)
  float* convY = (float*)qb;     // spans qb,kbuf (CBseg f32)
  float* Mbuf = ws + off;                  off += (size_t)CB * 32768;
  float* mv = ws + off;                    off += (size_t)CB * 512;
  int* topidx = (int*)(ws + off);          off += (size_t)CB * 384;
  int* idxbuf = (int*)(ws + off);          off += 196608ull;
  float* scbuf = ws + off;                 off += (size_t)CB * 1474560;  // CBNH*SMAX*4096
  float* Zbuf = ws + off;                  off += (size_t)CB * 360;      // CBNH*SMAX
  float* pvpart = ws + off;                off += (size_t)CB * 184320;   // PVJ*CBNH*SMAX*64

  // embedding
  {
    size_t total = (size_t)NB * 4096 * DM;
    embed_kernel<<<(int)(total / 256), 256, 0, stream>>>(x, emb_W, emb_b, h);
  }

  int L = 4096;
  for (int i = 0; i < 3; ++i) {
    int S = (i == 0) ? 45 : (i == 1) ? 40 : 35;
    int ngroups = NB / CB;
    int Mg = CB * L;
    size_t segL = (size_t)Mg * 512;

    // per-layer weight casts
    castT512<<<1024, 256, 0, stream>>>(Wq + (size_t)i * 262144, WqT);
    castT512<<<1024, 256, 0, stream>>>(Wk + (size_t)i * 262144, WkT);
    castT512<<<1024, 256, 0, stream>>>(Wv + (size_t)i * 262144, WvT);
    castT512<<<1024, 256, 0, stream>>>(Wo + (size_t)i * 262144, WoT);
    cast_bf16<<<1024, 256, 0, stream>>>(fW1 + (size_t)i * 1048576, W1b, 1048576);
    cast_bf16<<<1024, 256, 0, stream>>>(fW2 + (size_t)i * 1048576, W2b, 1048576);
    if (i < 2) cast_convW<<<3072, 256, 0, stream>>>(cW + (size_t)i * 786432, Wcb);

    // JAX randint key
    uint32_t fa, fbk;
    tf2x32(0u, 42u, 0u, (uint32_t)i, &fa, &fbk);
    uint32_t a0, b0, a1, b1;
    tf2x32(fa, fbk, 0u, 2u, &a0, &b0);
    tf2x32(fa, fbk, 1u, 3u, &a1, &b1);
    int n = L * S;
    gen_idx_kernel<<<(n + 255) / 256, 256, 0, stream>>>(idxbuf, b0, b1, n, L - 1);

    // ---- attention per batch group ----
    for (int g = 0; g < ngroups; ++g) {
      float* hg = h + (size_t)g * segL;
      cast_bf16<<<(int)(segL / 1024), 256, 0, stream>>>(hg, hb, segL);
      dim3 gq(4, Mg / 128);
      mfma_gemm<0, 0><<<gq, 256, 0, stream>>>(hb, WqT, bq + i * DM, nullptr, qb,
                                              nullptr, nullptr, 512, 512, 0);
      mfma_gemm<0, 0><<<gq, 256, 0, stream>>>(hb, WkT, bk + i * DM, nullptr, kbuf,
                                              nullptr, nullptr, 512, 512, 0);
      mfma_gemm<0, 0><<<gq, 256, 0, stream>>>(hb, WvT, bv + i * DM, nullptr, vb,
                                              nullptr, nullptr, 512, 512, 0);

      prob_scores<<<(CBNH * L) / 256, 256, 0, stream>>>(qb, kbuf, idxbuf, Mbuf, L, S);
      topk_kernel<<<CBNH, 256, 0, stream>>>(Mbuf, topidx, L, S);

      qk_scores<<<dim3(L / 256, CBNH), 256, 0, stream>>>(qb, kbuf, topidx, scbuf, L, S);
      softmax_exp<<<CBNH * S, 256, 0, stream>>>(scbuf, Zbuf, L);
      mean_v_kernel<<<CBNH, 256, 0, stream>>>(vb, mv, L);
      fill_ctx<<<(int)(segL / 256), 256, 0, stream>>>(ctxb, mv, L);
      pv_partial<<<dim3(PVJ, CBNH), 256, 0, stream>>>(scbuf, vb, pvpart, L, S, CBNH);
      pv_finish<<<(CBNH * S * 64 + 255) / 256, 256, 0, stream>>>(pvpart, Zbuf, topidx,
                                                                 ctxb, L, S, CBNH);

      mfma_gemm<0, 1><<<gq, 256, 0, stream>>>(ctxb, WoT, bo + i * DM, hg, nullptr,
                                              nullptr, nullptr, 512, 512, 0);
    }
    ln_inplace<<<NB * L, 256, 0, stream>>>(h, ln1g + i * DM, ln1b + i * DM);

    // ---- FF row-chunked ----
    int rows = NB * L;
    int R = CB * 4096;
    for (int r0 = 0; r0 < rows; r0 += R) {
      float* hr = h + (size_t)r0 * 512;
      cast_bf16<<<(int)(CBseg / 1024), 256, 0, stream>>>(hr, hb, CBseg);
      dim3 g1(16, R / 128);
      mfma_gemm<0, 2><<<g1, 256, 0, stream>>>(hb, W1b, fb1 + i * DFF_, nullptr, ybuf,
                                              nullptr, nullptr, 2048, 512, 0);
      dim3 g2(4, R / 128);
      mfma_gemm<0, 1><<<g2, 256, 0, stream>>>(ybuf, W2b, fb2 + i * DM, hr, nullptr,
                                              nullptr, nullptr, 512, 2048, 0);
    }
    ln_inplace<<<NB * L, 256, 0, stream>>>(h, ln2g + i * DM, ln2b + i * DM);

    // ---- conv + maxpool per batch group ----
    if (i < 2) {
      int Lh = L / 2;
      for (int g = 0; g < ngroups; ++g) {
        float* hg = h + (size_t)g * segL;
        cast_bf16<<<(int)(segL / 1024), 256, 0, stream>>>(hg, hb, segL);
        dim3 gc(4, Mg / 128);
        mfma_gemm<1, 3><<<gc, 256, 0, stream>>>(hb, Wcb, cb + i * DM, convY, nullptr,
                                                bng + i * DM, bnb + i * DM, 512, 1536, L);
        size_t tot = (size_t)CB * Lh * 512;
        maxpool_kernel<<<(int)(tot / 256), 256, 0, stream>>>(
            convY, h + (size_t)g * CB * Lh * 512, L);
      }
      L = Lh;
    }
  }

  final_ln_proj<<<NB * 47, 256, 0, stream>>>(h, flng, flnb, pW, pb, out, L);
}

// Round 5
// 6472.517 us; speedup vs baseline: 5.1076x; 1.2473x over previous
//
#include <hip/hip_runtime.h>
#include <cstdint>
#include <math.h>

#define NB 16
#define DM 512
#define NH 8
#define DFF_ 2048
#define SMAX 45
#define PVJ 8

typedef unsigned short ushort_t;
typedef __bf16 bf16x8 __attribute__((ext_vector_type(8)));
typedef float f32x4 __attribute__((ext_vector_type(4)));

// ---------------- bf16 helpers ----------------
__device__ __forceinline__ ushort_t f2b(float f) {  // RNE f32 -> bf16 bits
  uint32_t u = __float_as_uint(f);
  uint32_t r = (u + 0x7FFFu + ((u >> 16) & 1u)) >> 16;
  return (ushort_t)r;
}
__device__ __forceinline__ float bu2f(ushort_t x) {
  return __uint_as_float((uint32_t)x << 16);
}
__device__ __forceinline__ float b2f_lo(uint32_t u) { return __uint_as_float(u << 16); }
__device__ __forceinline__ float b2f_hi(uint32_t u) { return __uint_as_float(u & 0xFFFF0000u); }

// ---------------- threefry2x32 (JAX-compatible) ----------------
__host__ __device__ inline void tf2x32(uint32_t k0, uint32_t k1,
                                       uint32_t x0, uint32_t x1,
                                       uint32_t* o0, uint32_t* o1) {
  uint32_t ks0 = k0, ks1 = k1, ks2 = k0 ^ k1 ^ 0x1BD11BDAu;
  x0 += ks0; x1 += ks1;
#define TF_RND(r) { x0 += x1; x1 = (x1 << (r)) | (x1 >> (32 - (r))); x1 ^= x0; }
  TF_RND(13) TF_RND(15) TF_RND(26) TF_RND(6)
  x0 += ks1; x1 += ks2 + 1u;
  TF_RND(17) TF_RND(29) TF_RND(16) TF_RND(24)
  x0 += ks2; x1 += ks0 + 2u;
  TF_RND(13) TF_RND(15) TF_RND(26) TF_RND(6)
  x0 += ks0; x1 += ks1 + 3u;
  TF_RND(17) TF_RND(29) TF_RND(16) TF_RND(24)
  x0 += ks1; x1 += ks2 + 4u;
  TF_RND(13) TF_RND(15) TF_RND(26) TF_RND(6)
  x0 += ks2; x1 += ks0 + 5u;
#undef TF_RND
  *o0 = x0; *o1 = x1;
}

__global__ void gen_idx_kernel(int* __restrict__ idx, uint32_t k0, uint32_t k1,
                               int n, int mask) {
  int j = blockIdx.x * 256 + threadIdx.x;
  if (j >= n) return;
  int half = n >> 1;
  uint32_t o0, o1;
  if (j < half) {
    tf2x32(k0, k1, (uint32_t)j, (uint32_t)(j + half), &o0, &o1);
    idx[j] = (int)(o0 & (uint32_t)mask);
  } else {
    tf2x32(k0, k1, (uint32_t)(j - half), (uint32_t)j, &o0, &o1);
    idx[j] = (int)(o1 & (uint32_t)mask);
  }
}

// ---------------- block reduce helpers (256 threads, wave64) ----------------
__device__ inline float blk_reduce_sum(float v) {
  __shared__ float s[4];
  for (int o = 32; o > 0; o >>= 1) v += __shfl_down(v, o);
  int lane = threadIdx.x & 63, w = threadIdx.x >> 6;
  if (lane == 0) s[w] = v;
  __syncthreads();
  float r = s[0] + s[1] + s[2] + s[3];
  __syncthreads();
  return r;
}
__device__ inline float blk_reduce_max(float v) {
  __shared__ float s[4];
  for (int o = 32; o > 0; o >>= 1) v = fmaxf(v, __shfl_down(v, o));
  int lane = threadIdx.x & 63, w = threadIdx.x >> 6;
  if (lane == 0) s[w] = v;
  __syncthreads();
  float r = fmaxf(fmaxf(s[0], s[1]), fmaxf(s[2], s[3]));
  __syncthreads();
  return r;
}

// ---------------- embedding ----------------
__global__ void embed_kernel(const float* __restrict__ x, const float* __restrict__ W,
                             const float* __restrict__ bias, float* __restrict__ h) {
  size_t gid = (size_t)blockIdx.x * 256 + threadIdx.x;
  int o = (int)(gid & 511);
  size_t bl = gid >> 9;
  const float* xr = x + bl * 7;
  float acc = bias[o];
#pragma unroll
  for (int i = 0; i < 7; ++i) acc += xr[i] * W[i * 512 + o];
  h[gid] = acc;
}

// ---------------- cast kernels ----------------
__global__ void cast_bf16(const float* __restrict__ src, ushort_t* __restrict__ dst,
                          size_t n) {
  size_t i = ((size_t)blockIdx.x * 256 + threadIdx.x) * 4;
  if (i >= n) return;
  float4 v = *(const float4*)(src + i);
  ushort4 o;
  o.x = f2b(v.x); o.y = f2b(v.y); o.z = f2b(v.z); o.w = f2b(v.w);
  *(ushort4*)(dst + i) = o;
}

// Bt[n*512+k] = bf16(W[k*512+n])   (512x512)
__global__ void castT512(const float* __restrict__ W, ushort_t* __restrict__ Bt) {
  int gid = blockIdx.x * 256 + threadIdx.x;
  int n = gid >> 9, k = gid & 511;
  Bt[gid] = f2b(W[(size_t)k * 512 + n]);
}

// Bt[n*1536 + dt*512 + i] = bf16(convW[n][i][dt])
__global__ void cast_convW(const float* __restrict__ W, ushort_t* __restrict__ Bt) {
  int gid = blockIdx.x * 256 + threadIdx.x;
  int n = gid / 1536, k = gid - n * 1536;
  int dt = k >> 9, ii = k & 511;
  Bt[gid] = f2b(W[((size_t)n * 512 + ii) * 3 + dt]);
}

// ---------------- bf16 MFMA GEMM (m97 structure) ----------------
__device__ __forceinline__ float gelu_exact(float c) {
  return 0.5f * c * (1.0f + erff(c * 0.70710678118654752f));
}

template <int CONVMODE, int EPI>
__global__ __launch_bounds__(256) void mfma_gemm(
    const ushort_t* __restrict__ A, const ushort_t* __restrict__ Bt,
    const float* __restrict__ bias, float* __restrict__ Cf,
    ushort_t* __restrict__ Cb, const float* __restrict__ bng,
    const float* __restrict__ bnb, int N, int K, int L) {
  __shared__ __align__(16) ushort_t As[128 * 64];
  __shared__ __align__(16) ushort_t Bs[128 * 64];
  const int tid = threadIdx.x;
  const int lane = tid & 63;
  const int wid = tid >> 6;
  const int wr = wid >> 1, wc = wid & 1;
  const int bm = blockIdx.y, bn = blockIdx.x;
  const int ln = lane & 15, lh = lane >> 4;

  f32x4 acc[4][4] = {};

  for (int k0 = 0; k0 < K; k0 += 64) {
    __syncthreads();
#pragma unroll
    for (int it = 0; it < 4; ++it) {
      int c = it * 256 + tid;
      int row = c >> 3, kc = (c & 7) * 8;
      size_t ga;
      if (CONVMODE) {
        int m = bm * 128 + row;
        int b = m / L, tpos = m - b * L;
        int k = k0 + kc;
        int dt = k >> 9, ii = k & 511;
        int tr2 = tpos + dt - 1;
        if (tr2 < 0) tr2 += L;
        if (tr2 >= L) tr2 -= L;
        ga = ((size_t)(b * L + tr2)) * 512 + ii;
      } else {
        ga = (size_t)(bm * 128 + row) * K + k0 + kc;
      }
      __builtin_amdgcn_global_load_lds(
          (const __attribute__((address_space(1))) void*)(A + ga),
          (__attribute__((address_space(3))) void*)(As + c * 8), 16, 0, 0);
      size_t gb = (size_t)(bn * 128 + row) * K + k0 + kc;
      __builtin_amdgcn_global_load_lds(
          (const __attribute__((address_space(1))) void*)(Bt + gb),
          (__attribute__((address_space(3))) void*)(Bs + c * 8), 16, 0, 0);
    }
    __syncthreads();
#pragma unroll
    for (int kk = 0; kk < 2; ++kk) {
      bf16x8 af[4], bf_[4];
#pragma unroll
      for (int m = 0; m < 4; ++m)
        af[m] = *(const bf16x8*)&As[(wr * 64 + m * 16 + ln) * 64 + kk * 32 + lh * 8];
#pragma unroll
      for (int n = 0; n < 4; ++n)
        bf_[n] = *(const bf16x8*)&Bs[(wc * 64 + n * 16 + ln) * 64 + kk * 32 + lh * 8];
#pragma unroll
      for (int m = 0; m < 4; ++m)
#pragma unroll
        for (int n = 0; n < 4; ++n)
          acc[m][n] =
              __builtin_amdgcn_mfma_f32_16x16x32_bf16(af[m], bf_[n], acc[m][n], 0, 0, 0);
    }
  }

  const float bnscale = 0.9999950000374996f;  // 1/sqrt(1+1e-5)
#pragma unroll
  for (int m = 0; m < 4; ++m) {
    int row = bm * 128 + wr * 64 + m * 16 + lh * 4;
#pragma unroll
    for (int n = 0; n < 4; ++n) {
      int col = bn * 128 + wc * 64 + n * 16 + ln;
      float bsv = bias[col];
#pragma unroll
      for (int r = 0; r < 4; ++r) {
        float cval = acc[m][n][r] + bsv;
        size_t oi = (size_t)(row + r) * N + col;
        if (EPI == 0) {
          Cb[oi] = f2b(cval);
        } else if (EPI == 1) {
          Cf[oi] += cval;
        } else if (EPI == 2) {
          Cb[oi] = f2b(gelu_exact(cval));
        } else {
          float c2 = cval * bnscale * bng[col] + bnb[col];
          Cf[oi] = c2 > 0.0f ? c2 : expm1f(c2);
        }
      }
    }
  }
}

// ---------------- LN (in-place, row = 512) ----------------
__global__ __launch_bounds__(256) void ln_inplace(float* __restrict__ h,
                                                  const float* __restrict__ g,
                                                  const float* __restrict__ b) {
  size_t row = blockIdx.x;
  float* hr = h + row * 512;
  int t = threadIdx.x;
  float x0 = hr[t], x1 = hr[t + 256];
  float mean = blk_reduce_sum(x0 + x1) * (1.0f / 512.0f);
  float d0 = x0 - mean, d1 = x1 - mean;
  float var = blk_reduce_sum(d0 * d0 + d1 * d1) * (1.0f / 512.0f);
  float rstd = rsqrtf(var + 1e-5f);
  hr[t] = d0 * rstd * g[t] + b[t];
  hr[t + 256] = d1 * rstd * g[t + 256] + b[t + 256];
}

// ---------------- prob-sparse M scores (bf16 q,k) ----------------
__global__ __launch_bounds__(256) void prob_scores(const ushort_t* __restrict__ q,
                                                   const ushort_t* __restrict__ k,
                                                   const int* __restrict__ idx,
                                                   float* __restrict__ Mout,
                                                   int L, int S) {
  int gid = blockIdx.x * 256 + threadIdx.x;  // over CB*H*L
  int l = gid % L;
  int bh = gid / L;
  int hh = bh & 7;
  int b = bh >> 3;
  const ushort_t* qr = q + ((size_t)(b * L + l)) * 512 + hh * 64;
  float qq[64];
#pragma unroll
  for (int c = 0; c < 8; ++c) {
    uint4 u = ((const uint4*)qr)[c];
    qq[c * 8 + 0] = b2f_lo(u.x); qq[c * 8 + 1] = b2f_hi(u.x);
    qq[c * 8 + 2] = b2f_lo(u.y); qq[c * 8 + 3] = b2f_hi(u.y);
    qq[c * 8 + 4] = b2f_lo(u.z); qq[c * 8 + 5] = b2f_hi(u.z);
    qq[c * 8 + 6] = b2f_lo(u.w); qq[c * 8 + 7] = b2f_hi(u.w);
  }
  float m = -INFINITY, ssum = 0.0f;
  for (int s = 0; s < S; ++s) {
    int j = idx[l * S + s];
    const ushort_t* kr = k + ((size_t)(b * L + j)) * 512 + hh * 64;
    float dot = 0.0f;
#pragma unroll
    for (int c = 0; c < 8; ++c) {
      uint4 u = ((const uint4*)kr)[c];
      dot += qq[c * 8 + 0] * b2f_lo(u.x) + qq[c * 8 + 1] * b2f_hi(u.x) +
             qq[c * 8 + 2] * b2f_lo(u.y) + qq[c * 8 + 3] * b2f_hi(u.y) +
             qq[c * 8 + 4] * b2f_lo(u.z) + qq[c * 8 + 5] * b2f_hi(u.z) +
             qq[c * 8 + 6] * b2f_lo(u.w) + qq[c * 8 + 7] * b2f_hi(u.w);
    }
    m = fmaxf(m, dot);
    ssum += dot;
  }
  Mout[(size_t)bh * L + l] = m - ssum / (float)L;
}

// ---------------- top-k (iterative argmax, lower index wins ties) ----------------
__global__ __launch_bounds__(256) void topk_kernel(const float* __restrict__ Mbuf,
                                                   int* __restrict__ top_idx,
                                                   int L, int S) {
  int bh = blockIdx.x;
  __shared__ float vals[4096];
  __shared__ float rv[256];
  __shared__ int ri[256];
  const float* Mr = Mbuf + (size_t)bh * L;
  int t = threadIdx.x;
  for (int j = t; j < L; j += 256) vals[j] = Mr[j];
  __syncthreads();
  for (int it = 0; it < S; ++it) {
    float bv = -INFINITY;
    int bi = L;
    for (int j = t; j < L; j += 256) {
      float v = vals[j];
      if (v > bv || (v == bv && j < bi)) { bv = v; bi = j; }
    }
    rv[t] = bv; ri[t] = bi;
    __syncthreads();
    for (int s2 = 128; s2 > 0; s2 >>= 1) {
      if (t < s2) {
        float ov = rv[t + s2]; int oi = ri[t + s2];
        if (ov > rv[t] || (ov == rv[t] && oi < ri[t])) { rv[t] = ov; ri[t] = oi; }
      }
      __syncthreads();
    }
    if (t == 0) {
      top_idx[bh * S + it] = ri[0];
      vals[ri[0]] = -INFINITY;
    }
    __syncthreads();
  }
}

// ---------------- mean of V: stage 1 (coalesced column partial sums) ----------------
// grid (CB, L/256), 256 threads; thread t owns columns 2t, 2t+1.
__global__ __launch_bounds__(256) void mean_v_partial(const ushort_t* __restrict__ v,
                                                      float* __restrict__ part, int L) {
  int b = blockIdx.x;
  int chunk = blockIdx.y;
  int t = threadIdx.x;
  int c = t * 2;
  const ushort_t* base = v + ((size_t)b * L + (size_t)chunk * 256) * 512 + c;
  float a0 = 0.0f, a1 = 0.0f;
#pragma unroll 8
  for (int r = 0; r < 256; ++r) {
    uint32_t u = *(const uint32_t*)(base + (size_t)r * 512);
    a0 += b2f_lo(u);
    a1 += b2f_hi(u);
  }
  float* p = part + ((size_t)b * 16 + chunk) * 512 + c;
  p[0] = a0;
  p[1] = a1;
}

// ---------------- mean of V: stage 2 ----------------
__global__ void mean_v_finish(const float* __restrict__ part, float* __restrict__ mv,
                              int L, int nchunks) {
  int b = blockIdx.x;
  int c = threadIdx.x;  // 512 threads
  float s = 0.0f;
  for (int k = 0; k < nchunks; ++k) s += part[((size_t)b * 16 + k) * 512 + c];
  mv[b * 512 + c] = s / (float)L;
}

// ---------------- fill ctx (bf16) with broadcast mean ----------------
__global__ void fill_ctx(ushort_t* __restrict__ ctx, const float* __restrict__ mv,
                         int L) {
  size_t gid = (size_t)blockIdx.x * 256 + threadIdx.x;  // CB*L*512
  int c = (int)(gid & 511);
  size_t bl = gid >> 9;
  int b = (int)(bl / (size_t)L);
  ctx[gid] = f2b(mv[b * 512 + c]);
}

// ---------------- attention stage 1: scores for selected queries ----------------
__global__ __launch_bounds__(256) void qk_scores(const ushort_t* __restrict__ q,
                                                 const ushort_t* __restrict__ k,
                                                 const int* __restrict__ top_idx,
                                                 float* __restrict__ sc,
                                                 int L, int S) {
  __shared__ float qs[SMAX * 64];
  int bh = blockIdx.y;
  int hh = bh & 7, b = bh >> 3;
  int t = threadIdx.x;
  for (int e = t; e < S * 64; e += 256) {
    int u = e >> 6, d = e & 63;
    int l = top_idx[bh * S + u];
    qs[e] = bu2f(q[((size_t)(b * L + l)) * 512 + hh * 64 + d]);
  }
  __syncthreads();
  int j = blockIdx.x * 256 + t;
  const ushort_t* kr = k + ((size_t)(b * L + j)) * 512 + hh * 64;
  float kk[64];
#pragma unroll
  for (int c = 0; c < 8; ++c) {
    uint4 u4 = ((const uint4*)kr)[c];
    kk[c * 8 + 0] = b2f_lo(u4.x); kk[c * 8 + 1] = b2f_hi(u4.x);
    kk[c * 8 + 2] = b2f_lo(u4.y); kk[c * 8 + 3] = b2f_hi(u4.y);
    kk[c * 8 + 4] = b2f_lo(u4.z); kk[c * 8 + 5] = b2f_hi(u4.z);
    kk[c * 8 + 6] = b2f_lo(u4.w); kk[c * 8 + 7] = b2f_hi(u4.w);
  }
  float* srow = sc + (size_t)bh * S * L + j;
  for (int u = 0; u < S; ++u) {
    const float4* qu = (const float4*)(qs + u * 64);
    float dot = 0.0f;
#pragma unroll
    for (int c = 0; c < 16; ++c) {
      float4 qv = qu[c];
      dot += qv.x * kk[c * 4 + 0] + qv.y * kk[c * 4 + 1] +
             qv.z * kk[c * 4 + 2] + qv.w * kk[c * 4 + 3];
    }
    srow[(size_t)u * L] = dot * 0.125f;
  }
}

// ---------------- attention stage 2: softmax rows ----------------
__global__ __launch_bounds__(256) void softmax_exp(float* __restrict__ sc,
                                                   float* __restrict__ Zbuf, int L) {
  size_t row = blockIdx.x;  // bh*S + u
  float* sr = sc + row * L;
  int t = threadIdx.x;
  float m = -INFINITY;
  for (int j = t; j < L; j += 256) m = fmaxf(m, sr[j]);
  m = blk_reduce_max(m);
  float s = 0.0f;
  for (int j = t; j < L; j += 256) {
    float e = __expf(sr[j] - m);
    sr[j] = e;
    s += e;
  }
  s = blk_reduce_sum(s);
  if (t == 0) Zbuf[row] = s;
}

// ---------------- attention stage 3: PV partial sums ----------------
__global__ __launch_bounds__(256) void pv_partial(const float* __restrict__ sc,
                                                  const ushort_t* __restrict__ v,
                                                  float* __restrict__ part,
                                                  int L, int S, int CBNH) {
  __shared__ float scs[SMAX][64];
  int bh = blockIdx.y, js = blockIdx.x;
  int hh = bh & 7, b = bh >> 3;
  int t = threadIdx.x;
  int d = t & 63, ug = t >> 6;
  int jlen = L / PVJ;
  int j0 = js * jlen;
  float acc[12] = {};
  const float* scb = sc + (size_t)bh * S * L;
  for (int jc = 0; jc < jlen; jc += 64) {
    __syncthreads();
    for (int e = t; e < S * 64; e += 256) {
      int u = e >> 6, jj = e & 63;
      scs[u][jj] = scb[(size_t)u * L + j0 + jc + jj];
    }
    __syncthreads();
#pragma unroll 2
    for (int jb = 0; jb < 64; jb += 4) {
      float vv[4];
#pragma unroll
      for (int r = 0; r < 4; ++r)
        vv[r] = bu2f(v[((size_t)(b * L + j0 + jc + jb + r)) * 512 + hh * 64 + d]);
#pragma unroll
      for (int mi = 0; mi < 12; ++mi) {
        int u = ug + mi * 4;
        if (u < S) {
          float4 p4 = *(const float4*)&scs[u][jb];
          acc[mi] += p4.x * vv[0] + p4.y * vv[1] + p4.z * vv[2] + p4.w * vv[3];
        }
      }
    }
  }
  float* pb = part + ((size_t)js * CBNH + bh) * (SMAX * 64);
#pragma unroll
  for (int mi = 0; mi < 12; ++mi) {
    int u = ug + mi * 4;
    if (u < S) pb[u * 64 + d] = acc[mi];
  }
}

// ---------------- attention stage 4: combine, /Z, scatter ----------------
__global__ void pv_finish(const float* __restrict__ part, const float* __restrict__ Zbuf,
                          const int* __restrict__ top_idx, ushort_t* __restrict__ ctx,
                          int L, int S, int CBNH) {
  int gid = blockIdx.x * 256 + threadIdx.x;  // over CBNH*S*64
  if (gid >= CBNH * S * 64) return;
  int d = gid & 63;
  int r = gid >> 6;  // bh*S + u
  int u = r % S, bh = r / S;
  int hh = bh & 7, b = bh >> 3;
  float s = 0.0f;
#pragma unroll
  for (int js = 0; js < PVJ; ++js)
    s += part[((size_t)js * CBNH + bh) * (SMAX * 64) + u * 64 + d];
  int l = top_idx[bh * S + u];
  ctx[((size_t)(b * L + l)) * 512 + hh * 64 + d] = f2b(s / Zbuf[r]);
}

// ---------------- maxpool window 3 stride 2 ----------------
__global__ void maxpool_kernel(const float* __restrict__ y, float* __restrict__ hout,
                               int L) {
  size_t gid = (size_t)blockIdx.x * 256 + threadIdx.x;  // CB*(L/2)*512
  int Lh = L >> 1;
  int o = (int)(gid & 511);
  size_t bj = gid >> 9;
  int j = (int)(bj % (size_t)Lh);
  int b = (int)(bj / (size_t)Lh);
  const float* base = y + ((size_t)(b * L + 2 * j)) * 512 + o;
  float mx = base[0];
  if (j > 0) mx = fmaxf(mx, base[-512]);
  mx = fmaxf(mx, base[512]);
  hout[gid] = mx;
}

// ---------------- final LN + projection ----------------
__global__ __launch_bounds__(256) void final_ln_proj(const float* __restrict__ h,
                                                     const float* __restrict__ g,
                                                     const float* __restrict__ bb,
                                                     const float* __restrict__ pw,
                                                     const float* __restrict__ pb,
                                                     float* __restrict__ out, int L) {
  int b = blockIdx.x / 47, l = blockIdx.x % 47;
  const float* hr = h + ((size_t)(b * L + l)) * 512;
  int t = threadIdx.x;
  float x0 = hr[t], x1 = hr[t + 256];
  float mean = blk_reduce_sum(x0 + x1) * (1.0f / 512.0f);
  float d0 = x0 - mean, d1 = x1 - mean;
  float var = blk_reduce_sum(d0 * d0 + d1 * d1) * (1.0f / 512.0f);
  float rstd = rsqrtf(var + 1e-5f);
  float y0 = d0 * rstd * g[t] + bb[t];
  float y1 = d1 * rstd * g[t + 256] + bb[t + 256];
  float dot = blk_reduce_sum(y0 * pw[t] + y1 * pw[t + 256]);
  if (t == 0) out[b * 47 + l] = dot + pb[0];
}

// ---------------- launcher ----------------
extern "C" void kernel_launch(void* const* d_in, const int* in_sizes, int n_in,
                              void* d_out, int out_size, void* d_ws, size_t ws_size,
                              hipStream_t stream) {
  const float* x = (const float*)d_in[0];
  const float* emb_W = (const float*)d_in[1];
  const float* emb_b = (const float*)d_in[2];
  const float* Wq = (const float*)d_in[3];
  const float* bq = (const float*)d_in[4];
  const float* Wk = (const float*)d_in[5];
  const float* bk = (const float*)d_in[6];
  const float* Wv = (const float*)d_in[7];
  const float* bv = (const float*)d_in[8];
  const float* Wo = (const float*)d_in[9];
  const float* bo = (const float*)d_in[10];
  const float* fW1 = (const float*)d_in[11];
  const float* fb1 = (const float*)d_in[12];
  const float* fW2 = (const float*)d_in[13];
  const float* fb2 = (const float*)d_in[14];
  const float* ln1g = (const float*)d_in[15];
  const float* ln1b = (const float*)d_in[16];
  const float* ln2g = (const float*)d_in[17];
  const float* ln2b = (const float*)d_in[18];
  const float* cW = (const float*)d_in[19];
  const float* cb = (const float*)d_in[20];
  const float* bng = (const float*)d_in[21];
  const float* bnb = (const float*)d_in[22];
  const float* flng = (const float*)d_in[23];
  const float* flnb = (const float*)d_in[24];
  const float* pW = (const float*)d_in[25];
  const float* pb = (const float*)d_in[26];
  float* out = (float*)d_out;

  // batch-group size from ws_size (try 16, 8, 4, 2, 1)
  int CB = 16;
  while (CB > 1) {
    size_t need = 33554432ull + 1966080ull + (size_t)CB * 6943976ull +
                  196608ull + 2048ull;
    if (need * 4 <= ws_size) break;
    CB >>= 1;
  }
  const size_t CBseg = (size_t)CB * 2097152ull;  // CB*4096*512 (bf16 elems)
  const int CBNH = CB * NH;

  float* ws = (float*)d_ws;
  size_t off = 0;
  float* h = ws;                           off += 33554432ull;
  ushort_t* wbase = (ushort_t*)(ws + off); off += 1966080ull;
  ushort_t* WqT = wbase;
  ushort_t* WkT = wbase + 262144;
  ushort_t* WvT = wbase + 524288;
  ushort_t* WoT = wbase + 786432;
  ushort_t* W1b = wbase + 1048576;
  ushort_t* W2b = wbase + 2097152;
  ushort_t* Wcb = wbase + 3145728;
  ushort_t* gArea = (ushort_t*)(ws + off); off += (5ull * CBseg) / 2;
  ushort_t* hb = gArea;
  ushort_t* qb = gArea + CBseg;
  ushort_t* kbuf = gArea + 2 * CBseg;
  ushort_t* vb = gArea + 3 * CBseg;
  ushort_t* ctxb = gArea + 4 * CBseg;
  ushort_t* ybuf = qb;           // spans qb..ctxb (4*CBseg bf16)
  float* convY = (float*)qb;     // spans qb,kbuf (CBseg f32)
  float* Mbuf = ws + off;                  off += (size_t)CB * 32768;
  float* mv = ws + off;                    off += (size_t)CB * 512;
  int* topidx = (int*)(ws + off);          off += (size_t)CB * 384;
  int* idxbuf = (int*)(ws + off);          off += 196608ull;
  float* scbuf = ws + off;                 off += (size_t)CB * 1474560;  // CBNH*SMAX*4096
  float* Zbuf = ws + off;                  off += (size_t)CB * 360;      // CBNH*SMAX
  float* pvpart = ws + off;                off += (size_t)CB * 184320;   // PVJ*CBNH*SMAX*64
  float* mvpart = ws + off;                off += (size_t)CB * 8192;     // CB*16*512

  // embedding
  {
    size_t total = (size_t)NB * 4096 * DM;
    embed_kernel<<<(int)(total / 256), 256, 0, stream>>>(x, emb_W, emb_b, h);
  }

  int L = 4096;
  for (int i = 0; i < 3; ++i) {
    int S = (i == 0) ? 45 : (i == 1) ? 40 : 35;
    int ngroups = NB / CB;
    int Mg = CB * L;
    size_t segL = (size_t)Mg * 512;

    // per-layer weight casts
    castT512<<<1024, 256, 0, stream>>>(Wq + (size_t)i * 262144, WqT);
    castT512<<<1024, 256, 0, stream>>>(Wk + (size_t)i * 262144, WkT);
    castT512<<<1024, 256, 0, stream>>>(Wv + (size_t)i * 262144, WvT);
    castT512<<<1024, 256, 0, stream>>>(Wo + (size_t)i * 262144, WoT);
    cast_bf16<<<1024, 256, 0, stream>>>(fW1 + (size_t)i * 1048576, W1b, 1048576);
    cast_bf16<<<1024, 256, 0, stream>>>(fW2 + (size_t)i * 1048576, W2b, 1048576);
    if (i < 2) cast_convW<<<3072, 256, 0, stream>>>(cW + (size_t)i * 786432, Wcb);

    // JAX randint key
    uint32_t fa, fbk;
    tf2x32(0u, 42u, 0u, (uint32_t)i, &fa, &fbk);
    uint32_t a0, b0, a1, b1;
    tf2x32(fa, fbk, 0u, 2u, &a0, &b0);
    tf2x32(fa, fbk, 1u, 3u, &a1, &b1);
    int n = L * S;
    gen_idx_kernel<<<(n + 255) / 256, 256, 0, stream>>>(idxbuf, b0, b1, n, L - 1);

    // ---- attention per batch group ----
    for (int g = 0; g < ngroups; ++g) {
      float* hg = h + (size_t)g * segL;
      cast_bf16<<<(int)(segL / 1024), 256, 0, stream>>>(hg, hb, segL);
      dim3 gq(4, Mg / 128);
      mfma_gemm<0, 0><<<gq, 256, 0, stream>>>(hb, WqT, bq + i * DM, nullptr, qb,
                                              nullptr, nullptr, 512, 512, 0);
      mfma_gemm<0, 0><<<gq, 256, 0, stream>>>(hb, WkT, bk + i * DM, nullptr, kbuf,
                                              nullptr, nullptr, 512, 512, 0);
      mfma_gemm<0, 0><<<gq, 256, 0, stream>>>(hb, WvT, bv + i * DM, nullptr, vb,
                                              nullptr, nullptr, 512, 512, 0);

      prob_scores<<<(CBNH * L) / 256, 256, 0, stream>>>(qb, kbuf, idxbuf, Mbuf, L, S);
      topk_kernel<<<CBNH, 256, 0, stream>>>(Mbuf, topidx, L, S);

      qk_scores<<<dim3(L / 256, CBNH), 256, 0, stream>>>(qb, kbuf, topidx, scbuf, L, S);
      softmax_exp<<<CBNH * S, 256, 0, stream>>>(scbuf, Zbuf, L);
      mean_v_partial<<<dim3(CB, L / 256), 256, 0, stream>>>(vb, mvpart, L);
      mean_v_finish<<<CB, 512, 0, stream>>>(mvpart, mv, L, L / 256);
      fill_ctx<<<(int)(segL / 256), 256, 0, stream>>>(ctxb, mv, L);
      pv_partial<<<dim3(PVJ, CBNH), 256, 0, stream>>>(scbuf, vb, pvpart, L, S, CBNH);
      pv_finish<<<(CBNH * S * 64 + 255) / 256, 256, 0, stream>>>(pvpart, Zbuf, topidx,
                                                                 ctxb, L, S, CBNH);

      mfma_gemm<0, 1><<<gq, 256, 0, stream>>>(ctxb, WoT, bo + i * DM, hg, nullptr,
                                              nullptr, nullptr, 512, 512, 0);
    }
    ln_inplace<<<NB * L, 256, 0, stream>>>(h, ln1g + i * DM, ln1b + i * DM);

    // ---- FF row-chunked ----
    int rows = NB * L;
    int R = CB * 4096;
    if (R > rows) R = rows;
    for (int r0 = 0; r0 < rows; r0 += R) {
      float* hr = h + (size_t)r0 * 512;
      size_t rseg = (size_t)R * 512;
      cast_bf16<<<(int)(rseg / 1024), 256, 0, stream>>>(hr, hb, rseg);
      dim3 g1(16, R / 128);
      mfma_gemm<0, 2><<<g1, 256, 0, stream>>>(hb, W1b, fb1 + i * DFF_, nullptr, ybuf,
                                              nullptr, nullptr, 2048, 512, 0);
      dim3 g2(4, R / 128);
      mfma_gemm<0, 1><<<g2, 256, 0, stream>>>(ybuf, W2b, fb2 + i * DM, hr, nullptr,
                                              nullptr, nullptr, 512, 2048, 0);
    }
    ln_inplace<<<NB * L, 256, 0, stream>>>(h, ln2g + i * DM, ln2b + i * DM);

    // ---- conv + maxpool per batch group ----
    if (i < 2) {
      int Lh = L / 2;
      for (int g = 0; g < ngroups; ++g) {
        float* hg = h + (size_t)g * segL;
        cast_bf16<<<(int)(segL / 1024), 256, 0, stream>>>(hg, hb, segL);
        dim3 gc(4, Mg / 128);
        mfma_gemm<1, 3><<<gc, 256, 0, stream>>>(hb, Wcb, cb + i * DM, convY, nullptr,
                                                bng + i * DM, bnb + i * DM, 512, 1536, L);
        size_t tot = (size_t)CB * Lh * 512;
        maxpool_kernel<<<(int)(tot / 256), 256, 0, stream>>>(
            convY, h + (size_t)g * CB * Lh * 512, L);
      }
      L = Lh;
    }
  }

  final_ln_proj<<<NB * 47, 256, 0, stream>>>(h, flng, flnb, pW, pb, out, L);
}